// Round 14
// baseline (606.057 us; speedup 1.0000x reference)
//
#include <hip/hip_runtime.h>
#include <hip/hip_bf16.h>
#include <cstdint>

// SemlaLayer fused forward for MI355X (gfx950).
// R14: VGPR diet for 2-block/CU co-residency. R10's 2-barrier structure;
// W1 (48 VGPR) + W2 tiles 0-7 (32) stay in regs; wave-7's W2 tile 8 is
// streamed from L2 in-loop; kmsg/equis staging loads issue AFTER GEMM2
// (short live range); edges load stays early (HBM latency). waves_per_eu(4,8).

typedef __bf16 bf16x4_t __attribute__((ext_vector_type(4)));
typedef __bf16 bf16x8_t __attribute__((ext_vector_type(8)));
typedef float  f32x4_t  __attribute__((ext_vector_type(4)));

#define SP 76   // sS pitch in floats
#define KV 32   // k-tile rows

__device__ __forceinline__ int swzX(int row, int col) {   // pitch 192
    return row * 192 + (col ^ ((row & 7) << 3));
}
__device__ __forceinline__ int swzH(int row, int col) {   // pitch 256
    return (row << 8) + (col ^ ((row & 7) << 3));
}

__device__ __forceinline__ bf16x8_t cvt8(f32x4_t a, f32x4_t b) {
    bf16x8_t r;
    r[0] = (__bf16)a.x; r[1] = (__bf16)a.y; r[2] = (__bf16)a.z; r[3] = (__bf16)a.w;
    r[4] = (__bf16)b.x; r[5] = (__bf16)b.y; r[6] = (__bf16)b.z; r[7] = (__bf16)b.w;
    return r;
}
__device__ __forceinline__ bf16x4_t cvt4(f32x4_t a) {
    bf16x4_t r;
    r[0] = (__bf16)a.x; r[1] = (__bf16)a.y; r[2] = (__bf16)a.z; r[3] = (__bf16)a.w;
    return r;
}

// ---------------- pre-kernel ----------------
// blocks 0..255  : 4 (b,n) rows each -> kmsg, pTE, pTF (transposed), qc
// blocks 256..267: W1bf (256x192, W1 cols 64..255)
// blocks 268..276: W2bf (144x256, rows reordered: edge(72..135)|logit(0..71)|pad)
__global__ __launch_bounds__(256) void semla_pre(
    const float* __restrict__ invs, const float* __restrict__ equis,
    const float* __restrict__ Wq, const float* __restrict__ bq,
    const float* __restrict__ Wk, const float* __restrict__ bk,
    const float* __restrict__ Wc, const float* __restrict__ Wi, const float* __restrict__ bi,
    const float* __restrict__ W1, const float* __restrict__ W2,
    __bf16* __restrict__ W1bf, __bf16* __restrict__ W2bf,
    float* __restrict__ qc, float* __restrict__ kmsg,
    float* __restrict__ pTE, float* __restrict__ pTF)
{
    const int blk = blockIdx.x, tid = threadIdx.x;
    if (blk < 256) {
        const int r0 = blk * 4;
        __shared__ __align__(16) float sInv4[4][256];
        __shared__ __align__(16) float sEqu4[4][192];
        __shared__ __align__(16) float sQm4[4][64];
        #pragma unroll
        for (int j = 0; j < 4; ++j) {
            sInv4[j][tid] = invs[(size_t)(r0 + j) * 256 + tid];
            if (tid < 192) sEqu4[j][tid] = equis[(size_t)(r0 + j) * 192 + tid];
        }
        __syncthreads();
        {   // projF = invs @ Wi.T + bi  -> pTF[b][f][n]
            float acc[4] = {0.f, 0.f, 0.f, 0.f};
            const float* w = &Wi[tid * 256];
            for (int i = 0; i < 256; i += 4) {
                f32x4_t ww = *(const f32x4_t*)&w[i];
                #pragma unroll
                for (int j = 0; j < 4; ++j) {
                    const float* x = &sInv4[j][i];
                    acc[j] += ww.x * x[0] + ww.y * x[1] + ww.z * x[2] + ww.w * x[3];
                }
            }
            const float bb = bi[tid];
            #pragma unroll
            for (int j = 0; j < 4; ++j) {
                const int bb_ = (r0 + j) >> 8, nl = (r0 + j) & 255;
                pTF[((size_t)bb_ * 256 + tid) * 256 + nl] = acc[j] + bb;
            }
        }
        if (tid < 128) {   // qmsg (to LDS) / kmsg (to global)
            const int d = tid & 63;
            const float* w = (tid < 64) ? &Wq[d * 256] : &Wk[d * 256];
            float acc[4] = {0.f, 0.f, 0.f, 0.f};
            for (int i = 0; i < 256; i += 4) {
                f32x4_t ww = *(const f32x4_t*)&w[i];
                #pragma unroll
                for (int j = 0; j < 4; ++j) {
                    const float* x = &sInv4[j][i];
                    acc[j] += ww.x * x[0] + ww.y * x[1] + ww.z * x[2] + ww.w * x[3];
                }
            }
            if (tid < 64) {
                const float bb = bq[d];
                #pragma unroll
                for (int j = 0; j < 4; ++j) sQm4[j][d] = acc[j] + bb;
            } else {
                const float bb = bk[d];
                #pragma unroll
                for (int j = 0; j < 4; ++j) kmsg[(size_t)(r0 + j) * 64 + d] = acc[j] + bb;
            }
        }
        if (tid < 192) {   // projE = equis @ Wc.T -> pTE[b][c][d][n]
            const int c = tid >> 6, e = tid & 63;
            const float* w = &Wc[e * 64];
            float acc[4] = {0.f, 0.f, 0.f, 0.f};
            for (int dd = 0; dd < 64; dd += 4) {
                f32x4_t ww = *(const f32x4_t*)&w[dd];
                #pragma unroll
                for (int j = 0; j < 4; ++j) {
                    const float* x = &sEqu4[j][c * 64 + dd];
                    acc[j] += ww.x * x[0] + ww.y * x[1] + ww.z * x[2] + ww.w * x[3];
                }
            }
            #pragma unroll
            for (int j = 0; j < 4; ++j) {
                const int bb_ = (r0 + j) >> 8, nl = (r0 + j) & 255;
                pTE[(((size_t)bb_ * 3 + c) * 64 + e) * 256 + nl] = acc[j];
            }
        }
        __syncthreads();   // sQm4 ready
        {   // qc[r][o] = sum_{d<64} W1[o][d] * qmsg[r][d]
            const float* w = &W1[tid * 256];
            float acc[4] = {0.f, 0.f, 0.f, 0.f};
            for (int d = 0; d < 64; d += 4) {
                f32x4_t ww = *(const f32x4_t*)&w[d];
                #pragma unroll
                for (int j = 0; j < 4; ++j) {
                    const float* x = &sQm4[j][d];
                    acc[j] += ww.x * x[0] + ww.y * x[1] + ww.z * x[2] + ww.w * x[3];
                }
            }
            #pragma unroll
            for (int j = 0; j < 4; ++j) qc[(size_t)(r0 + j) * 256 + tid] = acc[j];
        }
    } else if (blk < 268) {   // W1bf: 256x192, source col 64+k
        const int base = (blk - 256) * 4096;
        #pragma unroll
        for (int it = 0; it < 16; ++it) {
            const int e = base + it * 256 + tid;   // < 49152
            const int o = e / 192, k = e % 192;
            W1bf[e] = (__bf16)W1[o * 256 + 64 + k];
        }
    } else if (blk < 277) {   // W2bf reordered
        const int base = (blk - 268) * 4096;
        #pragma unroll
        for (int it = 0; it < 16; ++it) {
            const int e = base + it * 256 + tid;   // < 36864
            const int o = e >> 8, cc = e & 255;
            const int src = (o < 64) ? (72 + o) : (o < 136 ? o - 64 : -1);
            W2bf[e] = (src >= 0) ? (__bf16)W2[src * 256 + cc] : (__bf16)0.f;
        }
    }
}

// ---------------- main fused kernel: one 8-wave workgroup per (b,q) ---------
__global__
__attribute__((amdgpu_flat_work_group_size(512, 512), amdgpu_waves_per_eu(4, 8)))
void semla_main(
    const float* __restrict__ equis, const float* __restrict__ edges,
    const int* __restrict__ adj,
    const __bf16* __restrict__ W1bf, const __bf16* __restrict__ W2bf,
    const float* __restrict__ qc, const float* __restrict__ kmsg,
    const float* __restrict__ pTE, const float* __restrict__ pTF,
    const float* __restrict__ b1, const float* __restrict__ b2,
    float* __restrict__ outE, float* __restrict__ outI, float* __restrict__ outEdge)
{
    const int bqid = ((blockIdx.x & 7) << 7) | (blockIdx.x >> 3);  // XCD swizzle
    const int b = bqid >> 8;
    const int tid = threadIdx.x;
    const int wave = tid >> 6, lane = tid & 63;
    const int arow = lane & 15, kgrp = lane >> 4;

    __shared__ __align__(16) __bf16 sX[KV * 192];   // 12KB X tile (K=192)
    __shared__ __align__(16) __bf16 sH[KV * 256];   // 16KB H tile
    __shared__ __align__(16) float  sS[KV * SP];    // p values
    __shared__ __align__(16) float  sB1[256];
    __shared__ __align__(16) float  sB2[144];
    __shared__ __align__(16) float  sEquiQ[192];
    __shared__ float sF[72], sL[72], sL2[72];
    __shared__ int   sAdj[2][KV];

    if (tid < 256) sB1[tid] = b1[tid] + qc[(size_t)bqid * 256 + tid];
    if (tid < 144) sB2[tid] = (tid < 64) ? b2[72 + tid] : (tid < 136 ? b2[tid - 64] : 0.f);
    if (tid < 192) sEquiQ[tid] = equis[(size_t)bqid * 192 + tid];

    // ---- loop-invariant weights in registers ----
    bf16x8_t w1r[6][2];                 // 32 FF cols per wave, K=192 (48 VGPR)
    #pragma unroll
    for (int ks = 0; ks < 6; ++ks)
        #pragma unroll
        for (int cf = 0; cf < 2; ++cf)
            w1r[ks][cf] = *(const bf16x8_t*)
                &W1bf[((wave << 5) + (cf << 4) + arow) * 192 + ks * 32 + (kgrp << 3)];
    bf16x8_t w2r[8];                    // wave w: tile w (32 VGPR)
    #pragma unroll
    for (int ks = 0; ks < 8; ++ks)
        w2r[ks] = *(const bf16x8_t*)
            &W2bf[(((wave << 4) + arow) << 8) + ks * 32 + (kgrp << 3)];
    // wave 7's second tile (rows 128..143) is streamed from L2 in-loop.

    // persistent per-thread state
    float m_run = -1e30f, l_run = 0.f, l2_run = 0.f;     // waves 4-7: ch=(wave-4)*16+arow
    float m_rn2 = -1e30f, l_rn2 = 0.f, l2_rn2 = 0.f;     // wave 7, arow<8: ch=64+arow
    float accE = 0.f;                                     // tid<192: (c_e,d_e)
    float accI = 0.f;                                     // tid>=256: fidx
    const int c_e = tid >> 6, d_e = tid & 63;
    const int fidx = tid - 256, h_i = (tid - 256) >> 5;

    // staging roles: row = (tid&255)>>3, colbase = (tid&7)<<3
    const int rowS = (tid & 255) >> 3;
    const int c8S = (tid & 7) << 3;
    const int pchunk = tid >> 1, prow = pchunk >> 3;
    const int pcol = 128 + ((pchunk & 7) << 3) + ((tid & 1) << 2);   // edges col in X

    __syncthreads();                       // init LDS (sEquiQ, sB1) visible

    // ---- prologue: stage X[0] + sAdj[0] ----
    {
        if (tid < 256) {
            const float* p = &kmsg[(size_t)(b * 256 + rowS) * 64 + c8S];
            *(bf16x8_t*)&sX[swzX(rowS, c8S)] =
                cvt8(*(const f32x4_t*)p, *(const f32x4_t*)(p + 4));
        } else {
            const float* ek = &equis[(size_t)(b * 256 + rowS) * 192 + c8S];
            f32x4_t e0a = *(const f32x4_t*)(ek),       e0b = *(const f32x4_t*)(ek + 4);
            f32x4_t e1a = *(const f32x4_t*)(ek + 64),  e1b = *(const f32x4_t*)(ek + 68);
            f32x4_t e2a = *(const f32x4_t*)(ek + 128), e2b = *(const f32x4_t*)(ek + 132);
            f32x4_t q0a = *(const f32x4_t*)&sEquiQ[c8S],       q0b = *(const f32x4_t*)&sEquiQ[c8S + 4];
            f32x4_t q1a = *(const f32x4_t*)&sEquiQ[64 + c8S],  q1b = *(const f32x4_t*)&sEquiQ[68 + c8S];
            f32x4_t q2a = *(const f32x4_t*)&sEquiQ[128 + c8S], q2b = *(const f32x4_t*)&sEquiQ[132 + c8S];
            *(bf16x8_t*)&sX[swzX(rowS, 64 + c8S)] =
                cvt8(e0a * q0a + e1a * q1a + e2a * q2a,
                     e0b * q0b + e1b * q1b + e2b * q2b);
        }
        f32x4_t ed = *(const f32x4_t*)&edges[((size_t)bqid * 256 + prow) * 64 + (pcol - 128)];
        *(bf16x4_t*)&sX[swzX(prow, pcol)] = cvt4(ed);
        if (tid < KV) sAdj[0][tid] = adj[(size_t)bqid * 256 + tid];
    }
    __syncthreads();                       // X[0] ready

    for (int kt = 0; kt < 8; ++kt) {
        const int k0 = kt * KV;
        const int cur = kt & 1;

        // ============ PHASE A: passB(kt-1) + GEMM1 + silu ============
        if (kt > 0) {
            const int k0P = k0 - KV;
            if (tid < 192) {
                float a = accE * sF[d_e];
                const float* pe = &pTE[(((size_t)b * 3 + c_e) * 64 + d_e) * 256 + k0P];
                #pragma unroll
                for (int t = 0; t < 8; ++t) {
                    f32x4_t w = *(const f32x4_t*)&pe[t * 4];
                    a += sS[(4 * t + 0) * SP + d_e] * w.x;
                    a += sS[(4 * t + 1) * SP + d_e] * w.y;
                    a += sS[(4 * t + 2) * SP + d_e] * w.z;
                    a += sS[(4 * t + 3) * SP + d_e] * w.w;
                }
                accE = a;
            }
            if (tid >= 256) {
                float a = accI * sF[64 + h_i];
                const float* pf = &pTF[((size_t)b * 256 + fidx) * 256 + k0P];
                #pragma unroll
                for (int t = 0; t < 8; ++t) {
                    f32x4_t w = *(const f32x4_t*)&pf[t * 4];
                    a += sS[(4 * t + 0) * SP + 64 + h_i] * w.x;
                    a += sS[(4 * t + 1) * SP + 64 + h_i] * w.y;
                    a += sS[(4 * t + 2) * SP + 64 + h_i] * w.z;
                    a += sS[(4 * t + 3) * SP + 64 + h_i] * w.w;
                }
                accI = a;
            }
        }

        // GEMM1 (K=192, W1 in regs) + silu -> sH
        f32x4_t acc1[2][2];
        {
            const f32x4_t z = {0.f, 0.f, 0.f, 0.f};
            acc1[0][0] = z; acc1[0][1] = z; acc1[1][0] = z; acc1[1][1] = z;
        }
        #pragma unroll
        for (int ks = 0; ks < 6; ++ks) {
            const int kk = ks * 32 + (kgrp << 3);
            bf16x8_t a0 = *(const bf16x8_t*)&sX[swzX(arow, kk)];
            bf16x8_t a1 = *(const bf16x8_t*)&sX[swzX(16 + arow, kk)];
            acc1[0][0] = __builtin_amdgcn_mfma_f32_16x16x32_bf16(a0, w1r[ks][0], acc1[0][0], 0, 0, 0);
            acc1[0][1] = __builtin_amdgcn_mfma_f32_16x16x32_bf16(a0, w1r[ks][1], acc1[0][1], 0, 0, 0);
            acc1[1][0] = __builtin_amdgcn_mfma_f32_16x16x32_bf16(a1, w1r[ks][0], acc1[1][0], 0, 0, 0);
            acc1[1][1] = __builtin_amdgcn_mfma_f32_16x16x32_bf16(a1, w1r[ks][1], acc1[1][1], 0, 0, 0);
        }
        #pragma unroll
        for (int rt = 0; rt < 2; ++rt)
            #pragma unroll
            for (int cf = 0; cf < 2; ++cf) {
                const int ccol = (wave << 5) + (cf << 4) + arow;
                const float bb = sB1[ccol];
                #pragma unroll
                for (int j = 0; j < 4; ++j) {
                    const int row = (rt << 4) + (kgrp << 2) + j;
                    float x = acc1[rt][cf][j] + bb;
                    sH[swzH(row, ccol)] = (__bf16)(x / (1.f + __expf(-x)));
                }
            }
        __syncthreads();                   // (1) H ready, passB done, sS free

        // ============ PHASE B: GEMM2 + softmax + staged loads + X[kt+1] =========
        // long-latency edges load first (HBM); covered by GEMM2+softmax
        f32x4_t edN;
        int adjN = 0;
        if (kt < 7) {
            edN = *(const f32x4_t*)
                &edges[((size_t)bqid * 256 + k0 + KV + prow) * 64 + (pcol - 128)];
            if (tid < KV) adjN = adj[(size_t)bqid * 256 + k0 + KV + tid];
        }

        // GEMM2 (W2 tiles 0-7 in regs; wave 7's tile 8 streamed from L2)
        f32x4_t acc2[2], acc2b[2];
        {
            const f32x4_t z = {0.f, 0.f, 0.f, 0.f};
            acc2[0] = z; acc2[1] = z; acc2b[0] = z; acc2b[1] = z;
        }
        #pragma unroll
        for (int ks = 0; ks < 8; ++ks) {
            const int kk = ks * 32 + (kgrp << 3);
            bf16x8_t a0 = *(const bf16x8_t*)&sH[swzH(arow, kk)];
            bf16x8_t a1 = *(const bf16x8_t*)&sH[swzH(16 + arow, kk)];
            acc2[0] = __builtin_amdgcn_mfma_f32_16x16x32_bf16(a0, w2r[ks], acc2[0], 0, 0, 0);
            acc2[1] = __builtin_amdgcn_mfma_f32_16x16x32_bf16(a1, w2r[ks], acc2[1], 0, 0, 0);
            if (wave == 7) {
                bf16x8_t bw = *(const bf16x8_t*)&W2bf[((128 + arow) << 8) + kk];
                acc2b[0] = __builtin_amdgcn_mfma_f32_16x16x32_bf16(a0, bw, acc2b[0], 0, 0, 0);
                acc2b[1] = __builtin_amdgcn_mfma_f32_16x16x32_bf16(a1, bw, acc2b[1], 0, 0, 0);
            }
        }

        // short-latency staged loads (L2-resident kmsg/equis) issue late
        f32x4_t kmA, kmB;                                   // tid<256
        f32x4_t e0a_, e0b_, e1a_, e1b_, e2a_, e2b_;         // tid>=256
        if (kt < 7) {
            const int kbN = b * 256 + k0 + KV;
            if (tid < 256) {
                const float* p = &kmsg[(size_t)(kbN + rowS) * 64 + c8S];
                kmA = *(const f32x4_t*)p;
                kmB = *(const f32x4_t*)(p + 4);
            } else {
                const float* ek = &equis[(size_t)(kbN + rowS) * 192 + c8S];
                e0a_ = *(const f32x4_t*)(ek);       e0b_ = *(const f32x4_t*)(ek + 4);
                e1a_ = *(const f32x4_t*)(ek + 64);  e1b_ = *(const f32x4_t*)(ek + 68);
                e2a_ = *(const f32x4_t*)(ek + 128); e2b_ = *(const f32x4_t*)(ek + 132);
            }
        }

        const int col = (wave << 4) + arow;
        if (wave < 4) {
            // edge channels: direct store
            const float bb2 = sB2[col];
            #pragma unroll
            for (int rt = 0; rt < 2; ++rt)
                #pragma unroll
                for (int j = 0; j < 4; ++j) {
                    const int r = (rt << 4) + (kgrp << 2) + j;
                    outEdge[((size_t)bqid * 256 + k0 + r) * 64 + col] = acc2[rt][j] + bb2;
                }
        } else {
            // logit channel ch: wave holds all 32 rows across kgrp lanes
            const int ch = col - 64;
            const float bb2 = sB2[col];
            float s_[8]; int ad_[8];
            float xm = -1e30f;
            #pragma unroll
            for (int rt = 0; rt < 2; ++rt)
                #pragma unroll
                for (int j = 0; j < 4; ++j) {
                    const int r = (rt << 4) + (kgrp << 2) + j;
                    const float v = acc2[rt][j] + bb2;
                    s_[rt * 4 + j] = v;
                    ad_[rt * 4 + j] = sAdj[cur][r];
                    if (ad_[rt * 4 + j]) xm = fmaxf(xm, v);
                }
            xm = fmaxf(xm, __shfl_xor(xm, 16));
            xm = fmaxf(xm, __shfl_xor(xm, 32));
            const float mN = fmaxf(m_run, xm);
            const float f = __expf(m_run - mN);
            float s1 = 0.f, s2 = 0.f;
            #pragma unroll
            for (int rt = 0; rt < 2; ++rt)
                #pragma unroll
                for (int j = 0; j < 4; ++j) {
                    const int r = (rt << 4) + (kgrp << 2) + j;
                    const float p = ad_[rt * 4 + j] ? __expf(s_[rt * 4 + j] - mN) : 0.f;
                    sS[r * SP + ch] = p;
                    s1 += p; s2 += p * p;
                }
            s1 += __shfl_xor(s1, 16); s1 += __shfl_xor(s1, 32);
            s2 += __shfl_xor(s2, 16); s2 += __shfl_xor(s2, 32);
            l_run = l_run * f + s1;
            l2_run = l2_run * f * f + s2;
            m_run = mN;
            if (kgrp == 0) sF[ch] = f;
        }
        if (wave == 7) {
            // tile 8: logit channels 64..71 (lanes arow<8 meaningful)
            const float bb3 = sB2[128 + (arow & 7)];
            float s_[8]; int ad_[8];
            float xm = -1e30f;
            #pragma unroll
            for (int rt = 0; rt < 2; ++rt)
                #pragma unroll
                for (int j = 0; j < 4; ++j) {
                    const int r = (rt << 4) + (kgrp << 2) + j;
                    const float v = acc2b[rt][j] + bb3;
                    s_[rt * 4 + j] = v;
                    ad_[rt * 4 + j] = sAdj[cur][r];
                    if (ad_[rt * 4 + j]) xm = fmaxf(xm, v);
                }
            xm = fmaxf(xm, __shfl_xor(xm, 16));
            xm = fmaxf(xm, __shfl_xor(xm, 32));
            const float mN = fmaxf(m_rn2, xm);
            const float f = __expf(m_rn2 - mN);
            float s1 = 0.f, s2 = 0.f;
            #pragma unroll
            for (int rt = 0; rt < 2; ++rt)
                #pragma unroll
                for (int j = 0; j < 4; ++j) {
                    const int r = (rt << 4) + (kgrp << 2) + j;
                    const float p = ad_[rt * 4 + j] ? __expf(s_[rt * 4 + j] - mN) : 0.f;
                    if (arow < 8) sS[r * SP + 64 + arow] = p;
                    s1 += p; s2 += p * p;
                }
            s1 += __shfl_xor(s1, 16); s1 += __shfl_xor(s1, 32);
            s2 += __shfl_xor(s2, 16); s2 += __shfl_xor(s2, 32);
            l_rn2 = l_rn2 * f + s1;
            l2_rn2 = l2_rn2 * f * f + s2;
            m_rn2 = mN;
            if (kgrp == 0 && arow < 8) sF[64 + arow] = f;
        }

        // write X[kt+1] from staged regs (sX free since barrier (1))
        if (kt < 7) {
            if (tid < 256) {
                *(bf16x8_t*)&sX[swzX(rowS, c8S)] = cvt8(kmA, kmB);
            } else {
                f32x4_t q0a = *(const f32x4_t*)&sEquiQ[c8S],       q0b = *(const f32x4_t*)&sEquiQ[c8S + 4];
                f32x4_t q1a = *(const f32x4_t*)&sEquiQ[64 + c8S],  q1b = *(const f32x4_t*)&sEquiQ[68 + c8S];
                f32x4_t q2a = *(const f32x4_t*)&sEquiQ[128 + c8S], q2b = *(const f32x4_t*)&sEquiQ[132 + c8S];
                *(bf16x8_t*)&sX[swzX(rowS, 64 + c8S)] =
                    cvt8(e0a_ * q0a + e1a_ * q1a + e2a_ * q2a,
                         e0b_ * q0b + e1b_ * q1b + e2b_ * q2b);
            }
            *(bf16x4_t*)&sX[swzX(prow, pcol)] = cvt4(edN);
            if (tid < KV) sAdj[cur ^ 1][tid] = adjN;
        }
        __syncthreads();                   // (2) sS/sF + X[kt+1] ready
    }

    // ---- final passB (kt=7 tile) ----
    {
        const int k0P = 224;
        if (tid < 192) {
            float a = accE * sF[d_e];
            const float* pe = &pTE[(((size_t)b * 3 + c_e) * 64 + d_e) * 256 + k0P];
            #pragma unroll
            for (int t = 0; t < 8; ++t) {
                f32x4_t w = *(const f32x4_t*)&pe[t * 4];
                a += sS[(4 * t + 0) * SP + d_e] * w.x;
                a += sS[(4 * t + 1) * SP + d_e] * w.y;
                a += sS[(4 * t + 2) * SP + d_e] * w.z;
                a += sS[(4 * t + 3) * SP + d_e] * w.w;
            }
            accE = a;
        }
        if (tid >= 256) {
            float a = accI * sF[64 + h_i];
            const float* pf = &pTF[((size_t)b * 256 + fidx) * 256 + k0P];
            #pragma unroll
            for (int t = 0; t < 8; ++t) {
                f32x4_t w = *(const f32x4_t*)&pf[t * 4];
                a += sS[(4 * t + 0) * SP + 64 + h_i] * w.x;
                a += sS[(4 * t + 1) * SP + 64 + h_i] * w.y;
                a += sS[(4 * t + 2) * SP + 64 + h_i] * w.z;
                a += sS[(4 * t + 3) * SP + 64 + h_i] * w.w;
            }
            accI = a;
        }
    }

    // ---- finalize: publish l, l2; write pre-GEMV outputs ----
    if (wave >= 4 && kgrp == 0) {
        const int ch = ((wave - 4) << 4) + arow;
        sL[ch] = l_run; sL2[ch] = l2_run;
        if (wave == 7 && arow < 8) { sL[64 + arow] = l_rn2; sL2[64 + arow] = l2_rn2; }
    }
    __syncthreads();
    if (tid < 192) {
        const float ll = sL[d_e];
        outE[(size_t)bqid * 192 + tid] = accE * sqrtf(sL2[d_e]) / (ll * ll);
    }
    if (tid >= 256) {
        const float ll = sL[64 + h_i];
        outI[(size_t)bqid * 256 + fidx] = accI * sqrtf(sL2[64 + h_i]) / (ll * ll);
    }
}

// ---------------- post-kernel: final Wa / Wo GEMVs, in place ----------------
__global__ __launch_bounds__(256) void semla_post(
    const float* __restrict__ Wa, const float* __restrict__ Wo,
    const float* __restrict__ bo,
    float* __restrict__ outE, float* __restrict__ outI)
{
    __shared__ __align__(16) float hE[4][192];
    __shared__ __align__(16) float hI[4][256];
    const int blk = blockIdx.x, tid = threadIdx.x;
    const int r0 = blk * 4;
    #pragma unroll
    for (int r = 0; r < 4; ++r) {
        if (tid < 192) hE[r][tid] = outE[(size_t)(r0 + r) * 192 + tid];
        hI[r][tid] = outI[(size_t)(r0 + r) * 256 + tid];
    }
    __syncthreads();
    if (tid < 192) {                        // equi_updates = hE @ Wa^T
        const int c = tid >> 6, e = tid & 63;
        float wa[64];
        #pragma unroll
        for (int d = 0; d < 64; d += 4) {
            f32x4_t w = *(const f32x4_t*)&Wa[e * 64 + d];
            wa[d] = w.x; wa[d + 1] = w.y; wa[d + 2] = w.z; wa[d + 3] = w.w;
        }
        #pragma unroll
        for (int r = 0; r < 4; ++r) {
            float s = 0.f;
            #pragma unroll
            for (int d = 0; d < 64; ++d) s += hE[r][c * 64 + d] * wa[d];
            outE[((size_t)(r0 + r) * 3 + c) * 64 + e] = s;
        }
    }
    {                                       // inv_updates = hI @ Wo^T + bo
        const float bb = bo[tid];
        const float* wo = &Wo[tid * 256];
        #pragma unroll
        for (int r = 0; r < 4; ++r) {
            float s = 0.f;
            for (int i = 0; i < 256; i += 4) {
                f32x4_t w = *(const f32x4_t*)&wo[i];
                s += w.x * hI[r][i] + w.y * hI[r][i + 1]
                   + w.z * hI[r][i + 2] + w.w * hI[r][i + 3];
            }
            outI[(size_t)(r0 + r) * 256 + tid] = s + bb;
        }
    }
}

extern "C" void kernel_launch(void* const* d_in, const int* in_sizes, int n_in,
                              void* d_out, int out_size, void* d_ws, size_t ws_size,
                              hipStream_t stream) {
    (void)in_sizes; (void)n_in; (void)out_size; (void)ws_size;
    const float* equis = (const float*)d_in[0];
    const float* invs  = (const float*)d_in[1];
    const float* edges = (const float*)d_in[2];
    const int*   adj   = (const int*)d_in[3];
    const float* Wq = (const float*)d_in[4];
    const float* bq = (const float*)d_in[5];
    const float* Wk = (const float*)d_in[6];
    const float* bk = (const float*)d_in[7];
    const float* W1 = (const float*)d_in[8];
    const float* b1 = (const float*)d_in[9];
    const float* W2 = (const float*)d_in[10];
    const float* b2 = (const float*)d_in[11];
    const float* Wc = (const float*)d_in[12];
    const float* Wa = (const float*)d_in[13];
    const float* Wi = (const float*)d_in[14];
    const float* bi = (const float*)d_in[15];
    const float* Wo = (const float*)d_in[16];
    const float* bo = (const float*)d_in[17];

    float* out = (float*)d_out;
    float* outE    = out;                  // (B,N,3,64)  = 196608
    float* outI    = out + 196608;         // (B,N,256)   = 262144
    float* outEdge = out + 458752;         // (B,N,N,64)  = 16777216

    char* ws = (char*)d_ws;
    __bf16* W1bf = (__bf16*)(ws);                    //  98304 B (256x192)
    __bf16* W2bf = (__bf16*)(ws + 98304);            //  73728 B (144x256)
    float* qc    = (float*)(ws + 172032);            // 1048576 B
    float* kmsg  = (float*)(ws + 1220608);           //  262144 B
    float* pTE   = (float*)(ws + 1482752);           //  786432 B
    float* pTF   = (float*)(ws + 2269184);           // 1048576 B -> 3317760 total

    semla_pre<<<277, 256, 0, stream>>>(invs, equis, Wq, bq, Wk, bk, Wc, Wi, bi,
                                       W1, W2, W1bf, W2bf, qc, kmsg, pTE, pTF);
    semla_main<<<1024, 512, 0, stream>>>(equis, edges, adj, W1bf, W2bf, qc, kmsg,
                                         pTE, pTF, b1, b2,
                                         outE, outI, outEdge);
    semla_post<<<256, 256, 0, stream>>>(Wa, Wo, bo, outE, outI);
}

// Round 15
// 516.666 us; speedup vs baseline: 1.1730x; 1.1730x over previous
//
#include <hip/hip_runtime.h>
#include <hip/hip_bf16.h>
#include <cstdint>

// SemlaLayer fused forward for MI355X (gfx950).
// R15: KV=128 (2 k-tiles, 7 barriers/block vs 17). Occupancy fixed at
// 1 block/CU (launch_bounds(512,2)) -> VGPR budget 256, LDS ~136KB.
// Fat phases: GEMM1 96 MFMA/wave, GEMM2 64-128; p stored transposed bf16
// for contiguous passB LDS reads; W2 tile 8 on wave 3 (edge wave).

typedef __bf16 bf16x8_t __attribute__((ext_vector_type(8)));
typedef float  f32x4_t  __attribute__((ext_vector_type(4)));

#define KV 128   // k-tile rows
#define PP 144   // sSt pitch (bf16 elems): 16B-aligned rows, 4-way bank alias

__device__ __forceinline__ int swzX(int row, int col) {   // pitch 192
    return row * 192 + (col ^ ((row & 7) << 3));
}
__device__ __forceinline__ int swzH(int row, int col) {   // pitch 256
    return (row << 8) + (col ^ ((row & 7) << 3));
}

__device__ __forceinline__ bf16x8_t cvt8(f32x4_t a, f32x4_t b) {
    bf16x8_t r;
    r[0] = (__bf16)a.x; r[1] = (__bf16)a.y; r[2] = (__bf16)a.z; r[3] = (__bf16)a.w;
    r[4] = (__bf16)b.x; r[5] = (__bf16)b.y; r[6] = (__bf16)b.z; r[7] = (__bf16)b.w;
    return r;
}

// ---------------- pre-kernel ----------------
// blocks 0..255  : 4 (b,n) rows each -> kmsg, pTE, pTF (transposed), qc
// blocks 256..267: W1bf (256x192, W1 cols 64..255)
// blocks 268..276: W2bf (144x256, rows reordered: edge(72..135)|logit(0..71)|pad)
__global__ __launch_bounds__(256) void semla_pre(
    const float* __restrict__ invs, const float* __restrict__ equis,
    const float* __restrict__ Wq, const float* __restrict__ bq,
    const float* __restrict__ Wk, const float* __restrict__ bk,
    const float* __restrict__ Wc, const float* __restrict__ Wi, const float* __restrict__ bi,
    const float* __restrict__ W1, const float* __restrict__ W2,
    __bf16* __restrict__ W1bf, __bf16* __restrict__ W2bf,
    float* __restrict__ qc, float* __restrict__ kmsg,
    float* __restrict__ pTE, float* __restrict__ pTF)
{
    const int blk = blockIdx.x, tid = threadIdx.x;
    if (blk < 256) {
        const int r0 = blk * 4;
        __shared__ __align__(16) float sInv4[4][256];
        __shared__ __align__(16) float sEqu4[4][192];
        __shared__ __align__(16) float sQm4[4][64];
        #pragma unroll
        for (int j = 0; j < 4; ++j) {
            sInv4[j][tid] = invs[(size_t)(r0 + j) * 256 + tid];
            if (tid < 192) sEqu4[j][tid] = equis[(size_t)(r0 + j) * 192 + tid];
        }
        __syncthreads();
        {   // projF = invs @ Wi.T + bi  -> pTF[b][f][n]
            float acc[4] = {0.f, 0.f, 0.f, 0.f};
            const float* w = &Wi[tid * 256];
            for (int i = 0; i < 256; i += 4) {
                f32x4_t ww = *(const f32x4_t*)&w[i];
                #pragma unroll
                for (int j = 0; j < 4; ++j) {
                    const float* x = &sInv4[j][i];
                    acc[j] += ww.x * x[0] + ww.y * x[1] + ww.z * x[2] + ww.w * x[3];
                }
            }
            const float bb = bi[tid];
            #pragma unroll
            for (int j = 0; j < 4; ++j) {
                const int bb_ = (r0 + j) >> 8, nl = (r0 + j) & 255;
                pTF[((size_t)bb_ * 256 + tid) * 256 + nl] = acc[j] + bb;
            }
        }
        if (tid < 128) {   // qmsg (to LDS) / kmsg (to global)
            const int d = tid & 63;
            const float* w = (tid < 64) ? &Wq[d * 256] : &Wk[d * 256];
            float acc[4] = {0.f, 0.f, 0.f, 0.f};
            for (int i = 0; i < 256; i += 4) {
                f32x4_t ww = *(const f32x4_t*)&w[i];
                #pragma unroll
                for (int j = 0; j < 4; ++j) {
                    const float* x = &sInv4[j][i];
                    acc[j] += ww.x * x[0] + ww.y * x[1] + ww.z * x[2] + ww.w * x[3];
                }
            }
            if (tid < 64) {
                const float bb = bq[d];
                #pragma unroll
                for (int j = 0; j < 4; ++j) sQm4[j][d] = acc[j] + bb;
            } else {
                const float bb = bk[d];
                #pragma unroll
                for (int j = 0; j < 4; ++j) kmsg[(size_t)(r0 + j) * 64 + d] = acc[j] + bb;
            }
        }
        if (tid < 192) {   // projE = equis @ Wc.T -> pTE[b][c][d][n]
            const int c = tid >> 6, e = tid & 63;
            const float* w = &Wc[e * 64];
            float acc[4] = {0.f, 0.f, 0.f, 0.f};
            for (int dd = 0; dd < 64; dd += 4) {
                f32x4_t ww = *(const f32x4_t*)&w[dd];
                #pragma unroll
                for (int j = 0; j < 4; ++j) {
                    const float* x = &sEqu4[j][c * 64 + dd];
                    acc[j] += ww.x * x[0] + ww.y * x[1] + ww.z * x[2] + ww.w * x[3];
                }
            }
            #pragma unroll
            for (int j = 0; j < 4; ++j) {
                const int bb_ = (r0 + j) >> 8, nl = (r0 + j) & 255;
                pTE[(((size_t)bb_ * 3 + c) * 64 + e) * 256 + nl] = acc[j];
            }
        }
        __syncthreads();   // sQm4 ready
        {   // qc[r][o] = sum_{d<64} W1[o][d] * qmsg[r][d]
            const float* w = &W1[tid * 256];
            float acc[4] = {0.f, 0.f, 0.f, 0.f};
            for (int d = 0; d < 64; d += 4) {
                f32x4_t ww = *(const f32x4_t*)&w[d];
                #pragma unroll
                for (int j = 0; j < 4; ++j) {
                    const float* x = &sQm4[j][d];
                    acc[j] += ww.x * x[0] + ww.y * x[1] + ww.z * x[2] + ww.w * x[3];
                }
            }
            #pragma unroll
            for (int j = 0; j < 4; ++j) qc[(size_t)(r0 + j) * 256 + tid] = acc[j];
        }
    } else if (blk < 268) {   // W1bf: 256x192, source col 64+k
        const int base = (blk - 256) * 4096;
        #pragma unroll
        for (int it = 0; it < 16; ++it) {
            const int e = base + it * 256 + tid;   // < 49152
            const int o = e / 192, k = e % 192;
            W1bf[e] = (__bf16)W1[o * 256 + 64 + k];
        }
    } else if (blk < 277) {   // W2bf reordered
        const int base = (blk - 268) * 4096;
        #pragma unroll
        for (int it = 0; it < 16; ++it) {
            const int e = base + it * 256 + tid;   // < 36864
            const int o = e >> 8, cc = e & 255;
            const int src = (o < 64) ? (72 + o) : (o < 136 ? o - 64 : -1);
            W2bf[e] = (src >= 0) ? (__bf16)W2[src * 256 + cc] : (__bf16)0.f;
        }
    }
}

// ---------------- main fused kernel: one 8-wave workgroup per (b,q) ---------
__global__ __launch_bounds__(512, 2) void semla_main(
    const float* __restrict__ equis, const float* __restrict__ edges,
    const int* __restrict__ adj,
    const __bf16* __restrict__ W1bf, const __bf16* __restrict__ W2bf,
    const float* __restrict__ qc, const float* __restrict__ kmsg,
    const float* __restrict__ pTE, const float* __restrict__ pTF,
    const float* __restrict__ b1, const float* __restrict__ b2,
    float* __restrict__ outE, float* __restrict__ outI, float* __restrict__ outEdge)
{
    const int bqid = ((blockIdx.x & 7) << 7) | (blockIdx.x >> 3);  // XCD swizzle
    const int b = bqid >> 8;
    const int tid = threadIdx.x;
    const int wave = tid >> 6, lane = tid & 63;
    const int arow = lane & 15, kgrp = lane >> 4;

    __shared__ __align__(16) __bf16 sX[KV * 192];    // 48KB X tile (K=192)
    __shared__ __align__(16) __bf16 sH[KV * 256];    // 64KB H tile
    __shared__ __align__(16) __bf16 sSt[72 * PP];    // 20.25KB p transposed [ch][k]
    __shared__ __align__(16) float  sB1[256];
    __shared__ __align__(16) float  sB2[144];
    __shared__ __align__(16) float  sEquiQ[192];
    __shared__ float sF[72], sL[72], sL2[72];
    __shared__ int   sAdj[KV];

    if (tid < 256) sB1[tid] = b1[tid] + qc[(size_t)bqid * 256 + tid];
    if (tid < 144) sB2[tid] = (tid < 64) ? b2[72 + tid] : (tid < 136 ? b2[tid - 64] : 0.f);
    if (tid < 192) sEquiQ[tid] = equis[(size_t)bqid * 192 + tid];

    // ---- loop-invariant weights in registers ----
    bf16x8_t w1r[6][2];                 // 32 FF cols per wave, K=192 (48 VGPR)
    #pragma unroll
    for (int ks = 0; ks < 6; ++ks)
        #pragma unroll
        for (int cf = 0; cf < 2; ++cf)
            w1r[ks][cf] = *(const bf16x8_t*)
                &W1bf[((wave << 5) + (cf << 4) + arow) * 192 + ks * 32 + (kgrp << 3)];
    bf16x8_t w2r[8];                    // wave w: tile w (32 VGPR)
    #pragma unroll
    for (int ks = 0; ks < 8; ++ks)
        w2r[ks] = *(const bf16x8_t*)
            &W2bf[(((wave << 4) + arow) << 8) + ks * 32 + (kgrp << 3)];
    bf16x8_t w2r2[8];                   // wave 3 also owns tile 8 (logit ch 64-71)
    #pragma unroll
    for (int ks = 0; ks < 8; ++ks)
        w2r2[ks] = *(const bf16x8_t*)&W2bf[((128 + arow) << 8) + ks * 32 + (kgrp << 3)];

    // persistent per-thread state
    float m_run = -1e30f, l_run = 0.f, l2_run = 0.f;     // waves 4-7: ch=(wave-4)*16+arow
    float m_rn2 = -1e30f, l_rn2 = 0.f, l2_rn2 = 0.f;     // wave 3, arow<8: ch=64+arow
    float accE = 0.f;                                     // tid<192: (c_e,d_e)
    float accI = 0.f;                                     // tid>=256: fidx
    const int c_e = tid >> 6, d_e = tid & 63;
    const int fidx = tid - 256, h_i = (tid - 256) >> 5;

    // staging: thread covers row rowT, column-chunks sub, sub+4, ..., sub+20
    const int rowT = tid >> 2, sub = tid & 3;

    __syncthreads();                       // init LDS visible

    // ---- STAGE macro: fill X[kt] + sAdj ----
    auto STAGE = [&](int kt) {
        const int k0s = kt * KV;
        const int kbs = b * 256 + k0s;
        #pragma unroll
        for (int ci = 0; ci < 6; ++ci) {
            const int cc = sub + ci * 4;          // 0..23
            const int c0 = cc << 3;
            if (cc < 8) {
                const float* p = &kmsg[(size_t)(kbs + rowT) * 64 + c0];
                *(bf16x8_t*)&sX[swzX(rowT, c0)] =
                    cvt8(*(const f32x4_t*)p, *(const f32x4_t*)(p + 4));
            } else if (cc < 16) {
                const int d0 = c0 - 64;
                const float* ek = &equis[(size_t)(kbs + rowT) * 192 + d0];
                f32x4_t e0a = *(const f32x4_t*)(ek),       e0b = *(const f32x4_t*)(ek + 4);
                f32x4_t e1a = *(const f32x4_t*)(ek + 64),  e1b = *(const f32x4_t*)(ek + 68);
                f32x4_t e2a = *(const f32x4_t*)(ek + 128), e2b = *(const f32x4_t*)(ek + 132);
                f32x4_t q0a = *(const f32x4_t*)&sEquiQ[d0],       q0b = *(const f32x4_t*)&sEquiQ[d0 + 4];
                f32x4_t q1a = *(const f32x4_t*)&sEquiQ[64 + d0],  q1b = *(const f32x4_t*)&sEquiQ[68 + d0];
                f32x4_t q2a = *(const f32x4_t*)&sEquiQ[128 + d0], q2b = *(const f32x4_t*)&sEquiQ[132 + d0];
                *(bf16x8_t*)&sX[swzX(rowT, c0)] =
                    cvt8(e0a * q0a + e1a * q1a + e2a * q2a,
                         e0b * q0b + e1b * q1b + e2b * q2b);
            } else {
                const float* p = &edges[((size_t)bqid * 256 + k0s + rowT) * 64 + (c0 - 128)];
                *(bf16x8_t*)&sX[swzX(rowT, c0)] =
                    cvt8(*(const f32x4_t*)p, *(const f32x4_t*)(p + 4));
            }
        }
        if (tid < KV) sAdj[tid] = adj[(size_t)bqid * 256 + k0s + tid];
    };

    STAGE(0);
    __syncthreads();                       // X[0] + adj ready

    for (int kt = 0; kt < 2; ++kt) {
        const int k0 = kt * KV;

        // ============ PHASE 1: GEMM1 (96 MFMA/wave) + silu -> sH ============
        f32x4_t acc1[8][2];
        {
            const f32x4_t z = {0.f, 0.f, 0.f, 0.f};
            #pragma unroll
            for (int rt = 0; rt < 8; ++rt) { acc1[rt][0] = z; acc1[rt][1] = z; }
        }
        #pragma unroll
        for (int ks = 0; ks < 6; ++ks) {
            const int kk = ks * 32 + (kgrp << 3);
            bf16x8_t a[8];
            #pragma unroll
            for (int rt = 0; rt < 8; ++rt)
                a[rt] = *(const bf16x8_t*)&sX[swzX((rt << 4) + arow, kk)];
            #pragma unroll
            for (int rt = 0; rt < 8; ++rt) {
                acc1[rt][0] = __builtin_amdgcn_mfma_f32_16x16x32_bf16(a[rt], w1r[ks][0], acc1[rt][0], 0, 0, 0);
                acc1[rt][1] = __builtin_amdgcn_mfma_f32_16x16x32_bf16(a[rt], w1r[ks][1], acc1[rt][1], 0, 0, 0);
            }
        }
        #pragma unroll
        for (int cf = 0; cf < 2; ++cf) {
            const int ccol = (wave << 5) + (cf << 4) + arow;
            const float bb = sB1[ccol];
            #pragma unroll
            for (int rt = 0; rt < 8; ++rt)
                #pragma unroll
                for (int j = 0; j < 4; ++j) {
                    const int row = (rt << 4) + (kgrp << 2) + j;
                    float x = acc1[rt][cf][j] + bb;
                    sH[swzH(row, ccol)] = (__bf16)(x / (1.f + __expf(-x)));
                }
        }
        __syncthreads();                   // (1) H ready; sX free

        // ============ PHASE 2: GEMM2 + in-reg softmax + edge stores ============
        f32x4_t acc2[8], acc2b[8];
        {
            const f32x4_t z = {0.f, 0.f, 0.f, 0.f};
            #pragma unroll
            for (int rt = 0; rt < 8; ++rt) { acc2[rt] = z; acc2b[rt] = z; }
        }
        #pragma unroll
        for (int ks = 0; ks < 8; ++ks) {
            const int kk = ks * 32 + (kgrp << 3);
            bf16x8_t a[8];
            #pragma unroll
            for (int rt = 0; rt < 8; ++rt)
                a[rt] = *(const bf16x8_t*)&sH[swzH((rt << 4) + arow, kk)];
            #pragma unroll
            for (int rt = 0; rt < 8; ++rt)
                acc2[rt] = __builtin_amdgcn_mfma_f32_16x16x32_bf16(a[rt], w2r[ks], acc2[rt], 0, 0, 0);
            if (wave == 3) {
                #pragma unroll
                for (int rt = 0; rt < 8; ++rt)
                    acc2b[rt] = __builtin_amdgcn_mfma_f32_16x16x32_bf16(a[rt], w2r2[ks], acc2b[rt], 0, 0, 0);
            }
        }
        const int col = (wave << 4) + arow;
        if (wave < 4) {
            // edge channels: direct store
            const float bb2 = sB2[col];
            #pragma unroll
            for (int rt = 0; rt < 8; ++rt)
                #pragma unroll
                for (int j = 0; j < 4; ++j) {
                    const int r = (rt << 4) + (kgrp << 2) + j;
                    outEdge[((size_t)bqid * 256 + k0 + r) * 64 + col] = acc2[rt][j] + bb2;
                }
        } else {
            // logit channel ch = col-64: wave holds all 128 rows across kgrp lanes
            const int ch = col - 64;
            const float bb2 = sB2[col];
            float s_[32];
            unsigned adm = 0;
            float xm = -1e30f;
            #pragma unroll
            for (int rt = 0; rt < 8; ++rt)
                #pragma unroll
                for (int j = 0; j < 4; ++j) {
                    const int r = (rt << 4) + (kgrp << 2) + j;
                    const float v = acc2[rt][j] + bb2;
                    s_[rt * 4 + j] = v;
                    if (sAdj[r]) { adm |= (1u << (rt * 4 + j)); xm = fmaxf(xm, v); }
                }
            xm = fmaxf(xm, __shfl_xor(xm, 16));
            xm = fmaxf(xm, __shfl_xor(xm, 32));
            const float mN = fmaxf(m_run, xm);
            const float f = __expf(m_run - mN);
            float s1 = 0.f, s2 = 0.f;
            #pragma unroll
            for (int rt = 0; rt < 8; ++rt)
                #pragma unroll
                for (int j = 0; j < 4; ++j) {
                    const int r = (rt << 4) + (kgrp << 2) + j;
                    const float p = ((adm >> (rt * 4 + j)) & 1u)
                                    ? __expf(s_[rt * 4 + j] - mN) : 0.f;
                    sSt[ch * PP + r] = (__bf16)p;
                    s1 += p; s2 += p * p;
                }
            s1 += __shfl_xor(s1, 16); s1 += __shfl_xor(s1, 32);
            s2 += __shfl_xor(s2, 16); s2 += __shfl_xor(s2, 32);
            l_run = l_run * f + s1;
            l2_run = l2_run * f * f + s2;
            m_run = mN;
            if (kgrp == 0) sF[ch] = f;
        }
        if (wave == 3) {
            // tile 8: logit channels 64..71 (lanes arow<8 meaningful)
            const float bb3 = sB2[128 + (arow & 7)];
            float s_[32];
            unsigned adm = 0;
            float xm = -1e30f;
            #pragma unroll
            for (int rt = 0; rt < 8; ++rt)
                #pragma unroll
                for (int j = 0; j < 4; ++j) {
                    const int r = (rt << 4) + (kgrp << 2) + j;
                    const float v = acc2b[rt][j] + bb3;
                    s_[rt * 4 + j] = v;
                    if (sAdj[r]) { adm |= (1u << (rt * 4 + j)); xm = fmaxf(xm, v); }
                }
            xm = fmaxf(xm, __shfl_xor(xm, 16));
            xm = fmaxf(xm, __shfl_xor(xm, 32));
            const float mN = fmaxf(m_rn2, xm);
            const float f = __expf(m_rn2 - mN);
            float s1 = 0.f, s2 = 0.f;
            #pragma unroll
            for (int rt = 0; rt < 8; ++rt)
                #pragma unroll
                for (int j = 0; j < 4; ++j) {
                    const int r = (rt << 4) + (kgrp << 2) + j;
                    const float p = ((adm >> (rt * 4 + j)) & 1u)
                                    ? __expf(s_[rt * 4 + j] - mN) : 0.f;
                    if (arow < 8) sSt[(64 + arow) * PP + r] = (__bf16)p;
                    s1 += p; s2 += p * p;
                }
            s1 += __shfl_xor(s1, 16); s1 += __shfl_xor(s1, 32);
            s2 += __shfl_xor(s2, 16); s2 += __shfl_xor(s2, 32);
            l_rn2 = l_rn2 * f + s1;
            l2_rn2 = l2_rn2 * f * f + s2;
            m_rn2 = mN;
            if (kgrp == 0 && arow < 8) sF[64 + arow] = f;
        }
        __syncthreads();                   // (2) sSt + sF ready

        // ============ PHASE 3: stage X[kt+1] + passB(kt) ============
        if (kt == 0) STAGE(1);
        if (tid < 192) {
            float a = accE * sF[d_e];
            const float* pe = &pTE[(((size_t)b * 3 + c_e) * 64 + d_e) * 256 + k0];
            const __bf16* ps = &sSt[d_e * PP];
            #pragma unroll
            for (int t = 0; t < 16; ++t) {
                bf16x8_t pv = *(const bf16x8_t*)&ps[t * 8];
                f32x4_t w0 = *(const f32x4_t*)&pe[t * 8];
                f32x4_t w1 = *(const f32x4_t*)&pe[t * 8 + 4];
                a += (float)pv[0] * w0.x + (float)pv[1] * w0.y
                   + (float)pv[2] * w0.z + (float)pv[3] * w0.w
                   + (float)pv[4] * w1.x + (float)pv[5] * w1.y
                   + (float)pv[6] * w1.z + (float)pv[7] * w1.w;
            }
            accE = a;
        }
        if (tid >= 256) {
            float a = accI * sF[64 + h_i];
            const float* pf = &pTF[((size_t)b * 256 + fidx) * 256 + k0];
            const __bf16* ps = &sSt[(64 + h_i) * PP];
            #pragma unroll
            for (int t = 0; t < 16; ++t) {
                bf16x8_t pv = *(const bf16x8_t*)&ps[t * 8];
                f32x4_t w0 = *(const f32x4_t*)&pf[t * 8];
                f32x4_t w1 = *(const f32x4_t*)&pf[t * 8 + 4];
                a += (float)pv[0] * w0.x + (float)pv[1] * w0.y
                   + (float)pv[2] * w0.z + (float)pv[3] * w0.w
                   + (float)pv[4] * w1.x + (float)pv[5] * w1.y
                   + (float)pv[6] * w1.z + (float)pv[7] * w1.w;
            }
            accI = a;
        }
        __syncthreads();                   // (3) X[kt+1] ready; sSt consumed
    }

    // ---- finalize: publish l, l2; write pre-GEMV outputs ----
    if (wave >= 4 && kgrp == 0) {
        const int ch = ((wave - 4) << 4) + arow;
        sL[ch] = l_run; sL2[ch] = l2_run;
    }
    if (wave == 3 && kgrp == 0 && arow < 8) { sL[64 + arow] = l_rn2; sL2[64 + arow] = l2_rn2; }
    __syncthreads();
    if (tid < 192) {
        const float ll = sL[d_e];
        outE[(size_t)bqid * 192 + tid] = accE * sqrtf(sL2[d_e]) / (ll * ll);
    }
    if (tid >= 256) {
        const float ll = sL[64 + h_i];
        outI[(size_t)bqid * 256 + fidx] = accI * sqrtf(sL2[64 + h_i]) / (ll * ll);
    }
}

// ---------------- post-kernel: final Wa / Wo GEMVs, in place ----------------
__global__ __launch_bounds__(256) void semla_post(
    const float* __restrict__ Wa, const float* __restrict__ Wo,
    const float* __restrict__ bo,
    float* __restrict__ outE, float* __restrict__ outI)
{
    __shared__ __align__(16) float hE[4][192];
    __shared__ __align__(16) float hI[4][256];
    const int blk = blockIdx.x, tid = threadIdx.x;
    const int r0 = blk * 4;
    #pragma unroll
    for (int r = 0; r < 4; ++r) {
        if (tid < 192) hE[r][tid] = outE[(size_t)(r0 + r) * 192 + tid];
        hI[r][tid] = outI[(size_t)(r0 + r) * 256 + tid];
    }
    __syncthreads();
    if (tid < 192) {                        // equi_updates = hE @ Wa^T
        const int c = tid >> 6, e = tid & 63;
        float wa[64];
        #pragma unroll
        for (int d = 0; d < 64; d += 4) {
            f32x4_t w = *(const f32x4_t*)&Wa[e * 64 + d];
            wa[d] = w.x; wa[d + 1] = w.y; wa[d + 2] = w.z; wa[d + 3] = w.w;
        }
        #pragma unroll
        for (int r = 0; r < 4; ++r) {
            float s = 0.f;
            #pragma unroll
            for (int d = 0; d < 64; ++d) s += hE[r][c * 64 + d] * wa[d];
            outE[((size_t)(r0 + r) * 3 + c) * 64 + e] = s;
        }
    }
    {                                       // inv_updates = hI @ Wo^T + bo
        const float bb = bo[tid];
        const float* wo = &Wo[tid * 256];
        #pragma unroll
        for (int r = 0; r < 4; ++r) {
            float s = 0.f;
            for (int i = 0; i < 256; i += 4) {
                f32x4_t w = *(const f32x4_t*)&wo[i];
                s += w.x * hI[r][i] + w.y * hI[r][i + 1]
                   + w.z * hI[r][i + 2] + w.w * hI[r][i + 3];
            }
            outI[(size_t)(r0 + r) * 256 + tid] = s + bb;
        }
    }
}

extern "C" void kernel_launch(void* const* d_in, const int* in_sizes, int n_in,
                              void* d_out, int out_size, void* d_ws, size_t ws_size,
                              hipStream_t stream) {
    (void)in_sizes; (void)n_in; (void)out_size; (void)ws_size;
    const float* equis = (const float*)d_in[0];
    const float* invs  = (const float*)d_in[1];
    const float* edges = (const float*)d_in[2];
    const int*   adj   = (const int*)d_in[3];
    const float* Wq = (const float*)d_in[4];
    const float* bq = (const float*)d_in[5];
    const float* Wk = (const float*)d_in[6];
    const float* bk = (const float*)d_in[7];
    const float* W1 = (const float*)d_in[8];
    const float* b1 = (const float*)d_in[9];
    const float* W2 = (const float*)d_in[10];
    const float* b2 = (const float*)d_in[11];
    const float* Wc = (const float*)d_in[12];
    const float* Wa = (const float*)d_in[13];
    const float* Wi = (const float*)d_in[14];
    const float* bi = (const float*)d_in[15];
    const float* Wo = (const float*)d_in[16];
    const float* bo = (const float*)d_in[17];

    float* out = (float*)d_out;
    float* outE    = out;                  // (B,N,3,64)  = 196608
    float* outI    = out + 196608;         // (B,N,256)   = 262144
    float* outEdge = out + 458752;         // (B,N,N,64)  = 16777216

    char* ws = (char*)d_ws;
    __bf16* W1bf = (__bf16*)(ws);                    //  98304 B (256x192)
    __bf16* W2bf = (__bf16*)(ws + 98304);            //  73728 B (144x256)
    float* qc    = (float*)(ws + 172032);            // 1048576 B
    float* kmsg  = (float*)(ws + 1220608);           //  262144 B
    float* pTE   = (float*)(ws + 1482752);           //  786432 B
    float* pTF   = (float*)(ws + 2269184);           // 1048576 B -> 3317760 total

    semla_pre<<<277, 256, 0, stream>>>(invs, equis, Wq, bq, Wk, bk, Wc, Wi, bi,
                                       W1, W2, W1bf, W2bf, qc, kmsg, pTE, pTF);
    semla_main<<<1024, 512, 0, stream>>>(equis, edges, adj, W1bf, W2bf, qc, kmsg,
                                         pTE, pTF, b1, b2,
                                         outE, outI, outEdge);
    semla_post<<<256, 256, 0, stream>>>(Wa, Wo, bo, outE, outI);
}

// Round 16
// 373.629 us; speedup vs baseline: 1.6221x; 1.3828x over previous
//
#include <hip/hip_runtime.h>
#include <hip/hip_bf16.h>
#include <cstdint>

// SemlaLayer fused forward for MI355X (gfx950).
// R16: 2-q fusion. 512 blocks x 512 threads; each block computes q0=2j,q1=2j+1
// with R9's 3-barrier structure -> 1.5 barriers/q, phase fixed-costs amortized
// 2x, kmsg/equis/pTE/pTF loads shared between the two q's. 1 block/CU (LDS
// 81KB); register peak ~200 < 256 unified file (no spill).

typedef __bf16 bf16x8_t __attribute__((ext_vector_type(8)));
typedef float  f32x4_t  __attribute__((ext_vector_type(4)));

#define SP 76   // sS pitch in floats
#define KV 32   // k-tile rows

__device__ __forceinline__ int swzX(int row, int col) {   // pitch 192
    return row * 192 + (col ^ ((row & 7) << 3));
}
__device__ __forceinline__ int swzH(int row, int col) {   // pitch 256
    return (row << 8) + (col ^ ((row & 7) << 3));
}

__device__ __forceinline__ bf16x8_t cvt8(f32x4_t a, f32x4_t b) {
    bf16x8_t r;
    r[0] = (__bf16)a.x; r[1] = (__bf16)a.y; r[2] = (__bf16)a.z; r[3] = (__bf16)a.w;
    r[4] = (__bf16)b.x; r[5] = (__bf16)b.y; r[6] = (__bf16)b.z; r[7] = (__bf16)b.w;
    return r;
}

// ---------------- pre-kernel ----------------
// blocks 0..255  : 4 (b,n) rows each -> kmsg, pTE, pTF (transposed), qc
// blocks 256..267: W1bf (256x192, W1 cols 64..255)
// blocks 268..276: W2bf (144x256, rows reordered: edge(72..135)|logit(0..71)|pad)
__global__ __launch_bounds__(256) void semla_pre(
    const float* __restrict__ invs, const float* __restrict__ equis,
    const float* __restrict__ Wq, const float* __restrict__ bq,
    const float* __restrict__ Wk, const float* __restrict__ bk,
    const float* __restrict__ Wc, const float* __restrict__ Wi, const float* __restrict__ bi,
    const float* __restrict__ W1, const float* __restrict__ W2,
    __bf16* __restrict__ W1bf, __bf16* __restrict__ W2bf,
    float* __restrict__ qc, float* __restrict__ kmsg,
    float* __restrict__ pTE, float* __restrict__ pTF)
{
    const int blk = blockIdx.x, tid = threadIdx.x;
    if (blk < 256) {
        const int r0 = blk * 4;
        __shared__ __align__(16) float sInv4[4][256];
        __shared__ __align__(16) float sEqu4[4][192];
        __shared__ __align__(16) float sQm4[4][64];
        #pragma unroll
        for (int j = 0; j < 4; ++j) {
            sInv4[j][tid] = invs[(size_t)(r0 + j) * 256 + tid];
            if (tid < 192) sEqu4[j][tid] = equis[(size_t)(r0 + j) * 192 + tid];
        }
        __syncthreads();
        {   // projF = invs @ Wi.T + bi  -> pTF[b][f][n]
            float acc[4] = {0.f, 0.f, 0.f, 0.f};
            const float* w = &Wi[tid * 256];
            for (int i = 0; i < 256; i += 4) {
                f32x4_t ww = *(const f32x4_t*)&w[i];
                #pragma unroll
                for (int j = 0; j < 4; ++j) {
                    const float* x = &sInv4[j][i];
                    acc[j] += ww.x * x[0] + ww.y * x[1] + ww.z * x[2] + ww.w * x[3];
                }
            }
            const float bb = bi[tid];
            #pragma unroll
            for (int j = 0; j < 4; ++j) {
                const int bb_ = (r0 + j) >> 8, nl = (r0 + j) & 255;
                pTF[((size_t)bb_ * 256 + tid) * 256 + nl] = acc[j] + bb;
            }
        }
        if (tid < 128) {   // qmsg (to LDS) / kmsg (to global)
            const int d = tid & 63;
            const float* w = (tid < 64) ? &Wq[d * 256] : &Wk[d * 256];
            float acc[4] = {0.f, 0.f, 0.f, 0.f};
            for (int i = 0; i < 256; i += 4) {
                f32x4_t ww = *(const f32x4_t*)&w[i];
                #pragma unroll
                for (int j = 0; j < 4; ++j) {
                    const float* x = &sInv4[j][i];
                    acc[j] += ww.x * x[0] + ww.y * x[1] + ww.z * x[2] + ww.w * x[3];
                }
            }
            if (tid < 64) {
                const float bb = bq[d];
                #pragma unroll
                for (int j = 0; j < 4; ++j) sQm4[j][d] = acc[j] + bb;
            } else {
                const float bb = bk[d];
                #pragma unroll
                for (int j = 0; j < 4; ++j) kmsg[(size_t)(r0 + j) * 64 + d] = acc[j] + bb;
            }
        }
        if (tid < 192) {   // projE = equis @ Wc.T -> pTE[b][c][d][n]
            const int c = tid >> 6, e = tid & 63;
            const float* w = &Wc[e * 64];
            float acc[4] = {0.f, 0.f, 0.f, 0.f};
            for (int dd = 0; dd < 64; dd += 4) {
                f32x4_t ww = *(const f32x4_t*)&w[dd];
                #pragma unroll
                for (int j = 0; j < 4; ++j) {
                    const float* x = &sEqu4[j][c * 64 + dd];
                    acc[j] += ww.x * x[0] + ww.y * x[1] + ww.z * x[2] + ww.w * x[3];
                }
            }
            #pragma unroll
            for (int j = 0; j < 4; ++j) {
                const int bb_ = (r0 + j) >> 8, nl = (r0 + j) & 255;
                pTE[(((size_t)bb_ * 3 + c) * 64 + e) * 256 + nl] = acc[j];
            }
        }
        __syncthreads();   // sQm4 ready
        {   // qc[r][o] = sum_{d<64} W1[o][d] * qmsg[r][d]
            const float* w = &W1[tid * 256];
            float acc[4] = {0.f, 0.f, 0.f, 0.f};
            for (int d = 0; d < 64; d += 4) {
                f32x4_t ww = *(const f32x4_t*)&w[d];
                #pragma unroll
                for (int j = 0; j < 4; ++j) {
                    const float* x = &sQm4[j][d];
                    acc[j] += ww.x * x[0] + ww.y * x[1] + ww.z * x[2] + ww.w * x[3];
                }
            }
            #pragma unroll
            for (int j = 0; j < 4; ++j) qc[(size_t)(r0 + j) * 256 + tid] = acc[j];
        }
    } else if (blk < 268) {   // W1bf: 256x192, source col 64+k
        const int base = (blk - 256) * 4096;
        #pragma unroll
        for (int it = 0; it < 16; ++it) {
            const int e = base + it * 256 + tid;   // < 49152
            const int o = e / 192, k = e % 192;
            W1bf[e] = (__bf16)W1[o * 256 + 64 + k];
        }
    } else if (blk < 277) {   // W2bf reordered
        const int base = (blk - 268) * 4096;
        #pragma unroll
        for (int it = 0; it < 16; ++it) {
            const int e = base + it * 256 + tid;   // < 36864
            const int o = e >> 8, cc = e & 255;
            const int src = (o < 64) ? (72 + o) : (o < 136 ? o - 64 : -1);
            W2bf[e] = (src >= 0) ? (__bf16)W2[src * 256 + cc] : (__bf16)0.f;
        }
    }
}

// ---------------- main fused kernel: 8-wave workgroup per (b, q0, q1) -------
__global__ __launch_bounds__(512, 2) void semla_main(
    const float* __restrict__ equis, const float* __restrict__ edges,
    const int* __restrict__ adj,
    const __bf16* __restrict__ W1bf, const __bf16* __restrict__ W2bf,
    const float* __restrict__ qc, const float* __restrict__ kmsg,
    const float* __restrict__ pTE, const float* __restrict__ pTF,
    const float* __restrict__ b1, const float* __restrict__ b2,
    float* __restrict__ outE, float* __restrict__ outI, float* __restrict__ outEdge)
{
    // XCD swizzle over 512 blocks: each XCD gets 64 contiguous q-pairs.
    const int pair = ((blockIdx.x & 7) << 6) | (blockIdx.x >> 3);   // 0..511
    const int b = pair >> 7;
    const int bq0 = b * 256 + ((pair & 127) << 1);
    const int bq1 = bq0 + 1;
    const int tid = threadIdx.x;
    const int wave = tid >> 6, lane = tid & 63;
    const int arow = lane & 15, kgrp = lane >> 4;

    __shared__ __align__(16) __bf16 sX0[KV * 192];   // 12KB
    __shared__ __align__(16) __bf16 sX1[KV * 192];   // 12KB
    __shared__ __align__(16) __bf16 sH0[KV * 256];   // 16KB
    __shared__ __align__(16) __bf16 sH1[KV * 256];   // 16KB
    __shared__ __align__(16) float  sS0[KV * SP];    // 9.5KB
    __shared__ __align__(16) float  sS1[KV * SP];    // 9.5KB
    __shared__ __align__(16) float  sB1q0[256], sB1q1[256];
    __shared__ __align__(16) float  sB2[144];
    __shared__ __align__(16) float  sEquiQ0[192], sEquiQ1[192];
    __shared__ float sF0[72], sF1[72], sL0[72], sL20[72], sL1[72], sL21[72];
    __shared__ int   sAdj0[KV], sAdj1[KV];

    if (tid < 256) {
        sB1q0[tid] = b1[tid] + qc[(size_t)bq0 * 256 + tid];
        sB1q1[tid] = b1[tid] + qc[(size_t)bq1 * 256 + tid];
    }
    if (tid < 144) sB2[tid] = (tid < 64) ? b2[72 + tid] : (tid < 136 ? b2[tid - 64] : 0.f);
    if (tid < 192) {
        sEquiQ0[tid] = equis[(size_t)bq0 * 192 + tid];
        sEquiQ1[tid] = equis[(size_t)bq1 * 192 + tid];
    }

    // ---- loop-invariant weights in registers ----
    bf16x8_t w1r[6][2];                 // 32 FF cols per wave, K=192 (48 VGPR)
    #pragma unroll
    for (int ks = 0; ks < 6; ++ks)
        #pragma unroll
        for (int cf = 0; cf < 2; ++cf)
            w1r[ks][cf] = *(const bf16x8_t*)
                &W1bf[((wave << 5) + (cf << 4) + arow) * 192 + ks * 32 + (kgrp << 3)];
    bf16x8_t w2r[8], w2r2[8];           // wave w: tile w; wave 7 also tile 8
    #pragma unroll
    for (int ks = 0; ks < 8; ++ks)
        w2r[ks] = *(const bf16x8_t*)
            &W2bf[(((wave << 4) + arow) << 8) + ks * 32 + (kgrp << 3)];
    if (wave == 7) {
        #pragma unroll
        for (int ks = 0; ks < 8; ++ks)
            w2r2[ks] = *(const bf16x8_t*)
                &W2bf[((128 + arow) << 8) + ks * 32 + (kgrp << 3)];
    }

    // persistent per-thread state (x2 q)
    float m0 = -1e30f, l0 = 0.f, l20 = 0.f;          // waves 4-7, q0
    float m1 = -1e30f, l1 = 0.f, l21 = 0.f;          // waves 4-7, q1
    float mb0 = -1e30f, lb0 = 0.f, l2b0 = 0.f;       // wave 7 tile8, q0
    float mb1 = -1e30f, lb1 = 0.f, l2b1 = 0.f;       // wave 7 tile8, q1
    float accE0 = 0.f, accE1 = 0.f;                   // tid<192
    float accI0 = 0.f, accI1 = 0.f;                   // tid>=256
    const int c_e = tid >> 6, d_e = tid & 63;
    const int fidx = tid - 256, h_i = (tid - 256) >> 5;

    __syncthreads();                       // init LDS visible

    for (int kt = 0; kt < 8; ++kt) {
        const int k0 = kt * KV;
        const int kb = b * 256 + k0;

        // ---- phase 1: stage X0/X1[kt] (+adj) and passB(kt-1) for both q ----
        #pragma unroll
        for (int gi = 0; gi < 2; ++gi) {
            const int g = (gi == 0) ? tid : 512 + tid;
            if (gi == 1 && tid >= 256) continue;
            const int row = g / 24, c8 = (g % 24) << 3;
            if (c8 < 64) {
                const float* p = &kmsg[(size_t)(kb + row) * 64 + c8];
                bf16x8_t v = cvt8(*(const f32x4_t*)p, *(const f32x4_t*)(p + 4));
                *(bf16x8_t*)&sX0[swzX(row, c8)] = v;
                *(bf16x8_t*)&sX1[swzX(row, c8)] = v;
            } else if (c8 < 128) {
                const int d0 = c8 - 64;
                const float* ek = &equis[(size_t)(kb + row) * 192 + d0];
                f32x4_t e0a = *(const f32x4_t*)(ek),       e0b = *(const f32x4_t*)(ek + 4);
                f32x4_t e1a = *(const f32x4_t*)(ek + 64),  e1b = *(const f32x4_t*)(ek + 68);
                f32x4_t e2a = *(const f32x4_t*)(ek + 128), e2b = *(const f32x4_t*)(ek + 132);
                {
                    f32x4_t q0a = *(const f32x4_t*)&sEquiQ0[d0],       q0b = *(const f32x4_t*)&sEquiQ0[d0 + 4];
                    f32x4_t q1a = *(const f32x4_t*)&sEquiQ0[64 + d0],  q1b = *(const f32x4_t*)&sEquiQ0[68 + d0];
                    f32x4_t q2a = *(const f32x4_t*)&sEquiQ0[128 + d0], q2b = *(const f32x4_t*)&sEquiQ0[132 + d0];
                    *(bf16x8_t*)&sX0[swzX(row, c8)] =
                        cvt8(e0a * q0a + e1a * q1a + e2a * q2a,
                             e0b * q0b + e1b * q1b + e2b * q2b);
                }
                {
                    f32x4_t q0a = *(const f32x4_t*)&sEquiQ1[d0],       q0b = *(const f32x4_t*)&sEquiQ1[d0 + 4];
                    f32x4_t q1a = *(const f32x4_t*)&sEquiQ1[64 + d0],  q1b = *(const f32x4_t*)&sEquiQ1[68 + d0];
                    f32x4_t q2a = *(const f32x4_t*)&sEquiQ1[128 + d0], q2b = *(const f32x4_t*)&sEquiQ1[132 + d0];
                    *(bf16x8_t*)&sX1[swzX(row, c8)] =
                        cvt8(e0a * q0a + e1a * q1a + e2a * q2a,
                             e0b * q0b + e1b * q1b + e2b * q2b);
                }
            } else {
                const float* p0 = &edges[((size_t)bq0 * 256 + k0 + row) * 64 + (c8 - 128)];
                const float* p1 = &edges[((size_t)bq1 * 256 + k0 + row) * 64 + (c8 - 128)];
                *(bf16x8_t*)&sX0[swzX(row, c8)] =
                    cvt8(*(const f32x4_t*)p0, *(const f32x4_t*)(p0 + 4));
                *(bf16x8_t*)&sX1[swzX(row, c8)] =
                    cvt8(*(const f32x4_t*)p1, *(const f32x4_t*)(p1 + 4));
            }
        }
        if (tid < KV) {
            sAdj0[tid] = adj[(size_t)bq0 * 256 + k0 + tid];
            sAdj1[tid] = adj[(size_t)bq1 * 256 + k0 + tid];
        }
        if (kt > 0) {
            const int k0P = k0 - KV;
            if (tid < 192) {
                float a0 = accE0 * sF0[d_e];
                float a1 = accE1 * sF1[d_e];
                const float* pe = &pTE[(((size_t)b * 3 + c_e) * 64 + d_e) * 256 + k0P];
                #pragma unroll
                for (int t = 0; t < 8; ++t) {
                    f32x4_t w = *(const f32x4_t*)&pe[t * 4];
                    a0 += sS0[(4 * t + 0) * SP + d_e] * w.x;
                    a0 += sS0[(4 * t + 1) * SP + d_e] * w.y;
                    a0 += sS0[(4 * t + 2) * SP + d_e] * w.z;
                    a0 += sS0[(4 * t + 3) * SP + d_e] * w.w;
                    a1 += sS1[(4 * t + 0) * SP + d_e] * w.x;
                    a1 += sS1[(4 * t + 1) * SP + d_e] * w.y;
                    a1 += sS1[(4 * t + 2) * SP + d_e] * w.z;
                    a1 += sS1[(4 * t + 3) * SP + d_e] * w.w;
                }
                accE0 = a0; accE1 = a1;
            }
            if (tid >= 256) {
                float a0 = accI0 * sF0[64 + h_i];
                float a1 = accI1 * sF1[64 + h_i];
                const float* pf = &pTF[((size_t)b * 256 + fidx) * 256 + k0P];
                #pragma unroll
                for (int t = 0; t < 8; ++t) {
                    f32x4_t w = *(const f32x4_t*)&pf[t * 4];
                    a0 += sS0[(4 * t + 0) * SP + 64 + h_i] * w.x;
                    a0 += sS0[(4 * t + 1) * SP + 64 + h_i] * w.y;
                    a0 += sS0[(4 * t + 2) * SP + 64 + h_i] * w.z;
                    a0 += sS0[(4 * t + 3) * SP + 64 + h_i] * w.w;
                    a1 += sS1[(4 * t + 0) * SP + 64 + h_i] * w.x;
                    a1 += sS1[(4 * t + 1) * SP + 64 + h_i] * w.y;
                    a1 += sS1[(4 * t + 2) * SP + 64 + h_i] * w.z;
                    a1 += sS1[(4 * t + 3) * SP + 64 + h_i] * w.w;
                }
                accI0 = a0; accI1 = a1;
            }
        }
        __syncthreads();                   // (A) X0/X1 staged, passB done

        // ---- phase 2: GEMM1 both q (interleaved) + silu -> sH0/sH1 ----
        f32x4_t A0[2][2], A1[2][2];
        {
            const f32x4_t z = {0.f, 0.f, 0.f, 0.f};
            #pragma unroll
            for (int rt = 0; rt < 2; ++rt)
                #pragma unroll
                for (int cf = 0; cf < 2; ++cf) { A0[rt][cf] = z; A1[rt][cf] = z; }
        }
        #pragma unroll
        for (int ks = 0; ks < 6; ++ks) {
            const int kk = ks * 32 + (kgrp << 3);
            bf16x8_t x00 = *(const bf16x8_t*)&sX0[swzX(arow, kk)];
            bf16x8_t x01 = *(const bf16x8_t*)&sX0[swzX(16 + arow, kk)];
            bf16x8_t x10 = *(const bf16x8_t*)&sX1[swzX(arow, kk)];
            bf16x8_t x11 = *(const bf16x8_t*)&sX1[swzX(16 + arow, kk)];
            A0[0][0] = __builtin_amdgcn_mfma_f32_16x16x32_bf16(x00, w1r[ks][0], A0[0][0], 0, 0, 0);
            A0[0][1] = __builtin_amdgcn_mfma_f32_16x16x32_bf16(x00, w1r[ks][1], A0[0][1], 0, 0, 0);
            A0[1][0] = __builtin_amdgcn_mfma_f32_16x16x32_bf16(x01, w1r[ks][0], A0[1][0], 0, 0, 0);
            A0[1][1] = __builtin_amdgcn_mfma_f32_16x16x32_bf16(x01, w1r[ks][1], A0[1][1], 0, 0, 0);
            A1[0][0] = __builtin_amdgcn_mfma_f32_16x16x32_bf16(x10, w1r[ks][0], A1[0][0], 0, 0, 0);
            A1[0][1] = __builtin_amdgcn_mfma_f32_16x16x32_bf16(x10, w1r[ks][1], A1[0][1], 0, 0, 0);
            A1[1][0] = __builtin_amdgcn_mfma_f32_16x16x32_bf16(x11, w1r[ks][0], A1[1][0], 0, 0, 0);
            A1[1][1] = __builtin_amdgcn_mfma_f32_16x16x32_bf16(x11, w1r[ks][1], A1[1][1], 0, 0, 0);
        }
        #pragma unroll
        for (int rt = 0; rt < 2; ++rt)
            #pragma unroll
            for (int cf = 0; cf < 2; ++cf) {
                const int ccol = (wave << 5) + (cf << 4) + arow;
                const float bb0 = sB1q0[ccol];
                const float bb1 = sB1q1[ccol];
                #pragma unroll
                for (int j = 0; j < 4; ++j) {
                    const int row = (rt << 4) + (kgrp << 2) + j;
                    float x0 = A0[rt][cf][j] + bb0;
                    float x1 = A1[rt][cf][j] + bb1;
                    sH0[swzH(row, ccol)] = (__bf16)(x0 / (1.f + __expf(-x0)));
                    sH1[swzH(row, ccol)] = (__bf16)(x1 / (1.f + __expf(-x1)));
                }
            }
        __syncthreads();                   // (B) H0/H1 ready

        // ---- phase 3: GEMM2 both q + edge stores + in-reg softmax ----
        f32x4_t C0[2], C1[2], Cb0[2], Cb1[2];
        {
            const f32x4_t z = {0.f, 0.f, 0.f, 0.f};
            C0[0] = z; C0[1] = z; C1[0] = z; C1[1] = z;
            Cb0[0] = z; Cb0[1] = z; Cb1[0] = z; Cb1[1] = z;
        }
        #pragma unroll
        for (int ks = 0; ks < 8; ++ks) {
            const int kk = ks * 32 + (kgrp << 3);
            bf16x8_t h00 = *(const bf16x8_t*)&sH0[swzH(arow, kk)];
            bf16x8_t h01 = *(const bf16x8_t*)&sH0[swzH(16 + arow, kk)];
            bf16x8_t h10 = *(const bf16x8_t*)&sH1[swzH(arow, kk)];
            bf16x8_t h11 = *(const bf16x8_t*)&sH1[swzH(16 + arow, kk)];
            C0[0] = __builtin_amdgcn_mfma_f32_16x16x32_bf16(h00, w2r[ks], C0[0], 0, 0, 0);
            C0[1] = __builtin_amdgcn_mfma_f32_16x16x32_bf16(h01, w2r[ks], C0[1], 0, 0, 0);
            C1[0] = __builtin_amdgcn_mfma_f32_16x16x32_bf16(h10, w2r[ks], C1[0], 0, 0, 0);
            C1[1] = __builtin_amdgcn_mfma_f32_16x16x32_bf16(h11, w2r[ks], C1[1], 0, 0, 0);
            if (wave == 7) {
                Cb0[0] = __builtin_amdgcn_mfma_f32_16x16x32_bf16(h00, w2r2[ks], Cb0[0], 0, 0, 0);
                Cb0[1] = __builtin_amdgcn_mfma_f32_16x16x32_bf16(h01, w2r2[ks], Cb0[1], 0, 0, 0);
                Cb1[0] = __builtin_amdgcn_mfma_f32_16x16x32_bf16(h10, w2r2[ks], Cb1[0], 0, 0, 0);
                Cb1[1] = __builtin_amdgcn_mfma_f32_16x16x32_bf16(h11, w2r2[ks], Cb1[1], 0, 0, 0);
            }
        }
        const int col = (wave << 4) + arow;
        if (wave < 4) {
            const float bb2 = sB2[col];
            #pragma unroll
            for (int rt = 0; rt < 2; ++rt)
                #pragma unroll
                for (int j = 0; j < 4; ++j) {
                    const int r = (rt << 4) + (kgrp << 2) + j;
                    outEdge[((size_t)bq0 * 256 + k0 + r) * 64 + col] = C0[rt][j] + bb2;
                    outEdge[((size_t)bq1 * 256 + k0 + r) * 64 + col] = C1[rt][j] + bb2;
                }
        } else {
            const int ch = col - 64;
            const float bb2 = sB2[col];
            // ---- q0 softmax ----
            {
                float s_[8]; int ad_[8];
                float xm = -1e30f;
                #pragma unroll
                for (int rt = 0; rt < 2; ++rt)
                    #pragma unroll
                    for (int j = 0; j < 4; ++j) {
                        const int r = (rt << 4) + (kgrp << 2) + j;
                        const float v = C0[rt][j] + bb2;
                        s_[rt * 4 + j] = v;
                        ad_[rt * 4 + j] = sAdj0[r];
                        if (ad_[rt * 4 + j]) xm = fmaxf(xm, v);
                    }
                xm = fmaxf(xm, __shfl_xor(xm, 16));
                xm = fmaxf(xm, __shfl_xor(xm, 32));
                const float mN = fmaxf(m0, xm);
                const float f = __expf(m0 - mN);
                float s1 = 0.f, s2 = 0.f;
                #pragma unroll
                for (int rt = 0; rt < 2; ++rt)
                    #pragma unroll
                    for (int j = 0; j < 4; ++j) {
                        const int r = (rt << 4) + (kgrp << 2) + j;
                        const float p = ad_[rt * 4 + j] ? __expf(s_[rt * 4 + j] - mN) : 0.f;
                        sS0[r * SP + ch] = p;
                        s1 += p; s2 += p * p;
                    }
                s1 += __shfl_xor(s1, 16); s1 += __shfl_xor(s1, 32);
                s2 += __shfl_xor(s2, 16); s2 += __shfl_xor(s2, 32);
                l0 = l0 * f + s1;
                l20 = l20 * f * f + s2;
                m0 = mN;
                if (kgrp == 0) sF0[ch] = f;
            }
            // ---- q1 softmax ----
            {
                float s_[8]; int ad_[8];
                float xm = -1e30f;
                #pragma unroll
                for (int rt = 0; rt < 2; ++rt)
                    #pragma unroll
                    for (int j = 0; j < 4; ++j) {
                        const int r = (rt << 4) + (kgrp << 2) + j;
                        const float v = C1[rt][j] + bb2;
                        s_[rt * 4 + j] = v;
                        ad_[rt * 4 + j] = sAdj1[r];
                        if (ad_[rt * 4 + j]) xm = fmaxf(xm, v);
                    }
                xm = fmaxf(xm, __shfl_xor(xm, 16));
                xm = fmaxf(xm, __shfl_xor(xm, 32));
                const float mN = fmaxf(m1, xm);
                const float f = __expf(m1 - mN);
                float s1 = 0.f, s2 = 0.f;
                #pragma unroll
                for (int rt = 0; rt < 2; ++rt)
                    #pragma unroll
                    for (int j = 0; j < 4; ++j) {
                        const int r = (rt << 4) + (kgrp << 2) + j;
                        const float p = ad_[rt * 4 + j] ? __expf(s_[rt * 4 + j] - mN) : 0.f;
                        sS1[r * SP + ch] = p;
                        s1 += p; s2 += p * p;
                    }
                s1 += __shfl_xor(s1, 16); s1 += __shfl_xor(s1, 32);
                s2 += __shfl_xor(s2, 16); s2 += __shfl_xor(s2, 32);
                l1 = l1 * f + s1;
                l21 = l21 * f * f + s2;
                m1 = mN;
                if (kgrp == 0) sF1[ch] = f;
            }
        }
        if (wave == 7) {
            const float bb3 = sB2[128 + (arow & 7)];
            // ---- q0 tile8 ----
            {
                float s_[8]; int ad_[8];
                float xm = -1e30f;
                #pragma unroll
                for (int rt = 0; rt < 2; ++rt)
                    #pragma unroll
                    for (int j = 0; j < 4; ++j) {
                        const int r = (rt << 4) + (kgrp << 2) + j;
                        const float v = Cb0[rt][j] + bb3;
                        s_[rt * 4 + j] = v;
                        ad_[rt * 4 + j] = sAdj0[r];
                        if (ad_[rt * 4 + j]) xm = fmaxf(xm, v);
                    }
                xm = fmaxf(xm, __shfl_xor(xm, 16));
                xm = fmaxf(xm, __shfl_xor(xm, 32));
                const float mN = fmaxf(mb0, xm);
                const float f = __expf(mb0 - mN);
                float s1 = 0.f, s2 = 0.f;
                #pragma unroll
                for (int rt = 0; rt < 2; ++rt)
                    #pragma unroll
                    for (int j = 0; j < 4; ++j) {
                        const int r = (rt << 4) + (kgrp << 2) + j;
                        const float p = ad_[rt * 4 + j] ? __expf(s_[rt * 4 + j] - mN) : 0.f;
                        if (arow < 8) sS0[r * SP + 64 + arow] = p;
                        s1 += p; s2 += p * p;
                    }
                s1 += __shfl_xor(s1, 16); s1 += __shfl_xor(s1, 32);
                s2 += __shfl_xor(s2, 16); s2 += __shfl_xor(s2, 32);
                lb0 = lb0 * f + s1;
                l2b0 = l2b0 * f * f + s2;
                mb0 = mN;
                if (kgrp == 0 && arow < 8) sF0[64 + arow] = f;
            }
            // ---- q1 tile8 ----
            {
                float s_[8]; int ad_[8];
                float xm = -1e30f;
                #pragma unroll
                for (int rt = 0; rt < 2; ++rt)
                    #pragma unroll
                    for (int j = 0; j < 4; ++j) {
                        const int r = (rt << 4) + (kgrp << 2) + j;
                        const float v = Cb1[rt][j] + bb3;
                        s_[rt * 4 + j] = v;
                        ad_[rt * 4 + j] = sAdj1[r];
                        if (ad_[rt * 4 + j]) xm = fmaxf(xm, v);
                    }
                xm = fmaxf(xm, __shfl_xor(xm, 16));
                xm = fmaxf(xm, __shfl_xor(xm, 32));
                const float mN = fmaxf(mb1, xm);
                const float f = __expf(mb1 - mN);
                float s1 = 0.f, s2 = 0.f;
                #pragma unroll
                for (int rt = 0; rt < 2; ++rt)
                    #pragma unroll
                    for (int j = 0; j < 4; ++j) {
                        const int r = (rt << 4) + (kgrp << 2) + j;
                        const float p = ad_[rt * 4 + j] ? __expf(s_[rt * 4 + j] - mN) : 0.f;
                        if (arow < 8) sS1[r * SP + 64 + arow] = p;
                        s1 += p; s2 += p * p;
                    }
                s1 += __shfl_xor(s1, 16); s1 += __shfl_xor(s1, 32);
                s2 += __shfl_xor(s2, 16); s2 += __shfl_xor(s2, 32);
                lb1 = lb1 * f + s1;
                l2b1 = l2b1 * f * f + s2;
                mb1 = mN;
                if (kgrp == 0 && arow < 8) sF1[64 + arow] = f;
            }
        }
        __syncthreads();                   // (C) p + sF ready
    }

    // ---- final passB (kt=7 tile) for both q ----
    {
        const int k0P = 224;
        if (tid < 192) {
            float a0 = accE0 * sF0[d_e];
            float a1 = accE1 * sF1[d_e];
            const float* pe = &pTE[(((size_t)b * 3 + c_e) * 64 + d_e) * 256 + k0P];
            #pragma unroll
            for (int t = 0; t < 8; ++t) {
                f32x4_t w = *(const f32x4_t*)&pe[t * 4];
                a0 += sS0[(4 * t + 0) * SP + d_e] * w.x;
                a0 += sS0[(4 * t + 1) * SP + d_e] * w.y;
                a0 += sS0[(4 * t + 2) * SP + d_e] * w.z;
                a0 += sS0[(4 * t + 3) * SP + d_e] * w.w;
                a1 += sS1[(4 * t + 0) * SP + d_e] * w.x;
                a1 += sS1[(4 * t + 1) * SP + d_e] * w.y;
                a1 += sS1[(4 * t + 2) * SP + d_e] * w.z;
                a1 += sS1[(4 * t + 3) * SP + d_e] * w.w;
            }
            accE0 = a0; accE1 = a1;
        }
        if (tid >= 256) {
            float a0 = accI0 * sF0[64 + h_i];
            float a1 = accI1 * sF1[64 + h_i];
            const float* pf = &pTF[((size_t)b * 256 + fidx) * 256 + k0P];
            #pragma unroll
            for (int t = 0; t < 8; ++t) {
                f32x4_t w = *(const f32x4_t*)&pf[t * 4];
                a0 += sS0[(4 * t + 0) * SP + 64 + h_i] * w.x;
                a0 += sS0[(4 * t + 1) * SP + 64 + h_i] * w.y;
                a0 += sS0[(4 * t + 2) * SP + 64 + h_i] * w.z;
                a0 += sS0[(4 * t + 3) * SP + 64 + h_i] * w.w;
                a1 += sS1[(4 * t + 0) * SP + 64 + h_i] * w.x;
                a1 += sS1[(4 * t + 1) * SP + 64 + h_i] * w.y;
                a1 += sS1[(4 * t + 2) * SP + 64 + h_i] * w.z;
                a1 += sS1[(4 * t + 3) * SP + 64 + h_i] * w.w;
            }
            accI0 = a0; accI1 = a1;
        }
    }

    // ---- finalize: publish l, l2; write pre-GEMV outputs (both q) ----
    if (wave >= 4 && kgrp == 0) {
        const int ch = ((wave - 4) << 4) + arow;
        sL0[ch] = l0; sL20[ch] = l20;
        sL1[ch] = l1; sL21[ch] = l21;
        if (wave == 7 && arow < 8) {
            sL0[64 + arow] = lb0; sL20[64 + arow] = l2b0;
            sL1[64 + arow] = lb1; sL21[64 + arow] = l2b1;
        }
    }
    __syncthreads();
    if (tid < 192) {
        const float la = sL0[d_e], lbq = sL1[d_e];
        outE[(size_t)bq0 * 192 + tid] = accE0 * sqrtf(sL20[d_e]) / (la * la);
        outE[(size_t)bq1 * 192 + tid] = accE1 * sqrtf(sL21[d_e]) / (lbq * lbq);
    }
    if (tid >= 256) {
        const float la = sL0[64 + h_i], lbq = sL1[64 + h_i];
        outI[(size_t)bq0 * 256 + fidx] = accI0 * sqrtf(sL20[64 + h_i]) / (la * la);
        outI[(size_t)bq1 * 256 + fidx] = accI1 * sqrtf(sL21[64 + h_i]) / (lbq * lbq);
    }
}

// ---------------- post-kernel: final Wa / Wo GEMVs, in place ----------------
__global__ __launch_bounds__(256) void semla_post(
    const float* __restrict__ Wa, const float* __restrict__ Wo,
    const float* __restrict__ bo,
    float* __restrict__ outE, float* __restrict__ outI)
{
    __shared__ __align__(16) float hE[4][192];
    __shared__ __align__(16) float hI[4][256];
    const int blk = blockIdx.x, tid = threadIdx.x;
    const int r0 = blk * 4;
    #pragma unroll
    for (int r = 0; r < 4; ++r) {
        if (tid < 192) hE[r][tid] = outE[(size_t)(r0 + r) * 192 + tid];
        hI[r][tid] = outI[(size_t)(r0 + r) * 256 + tid];
    }
    __syncthreads();
    if (tid < 192) {                        // equi_updates = hE @ Wa^T
        const int c = tid >> 6, e = tid & 63;
        float wa[64];
        #pragma unroll
        for (int d = 0; d < 64; d += 4) {
            f32x4_t w = *(const f32x4_t*)&Wa[e * 64 + d];
            wa[d] = w.x; wa[d + 1] = w.y; wa[d + 2] = w.z; wa[d + 3] = w.w;
        }
        #pragma unroll
        for (int r = 0; r < 4; ++r) {
            float s = 0.f;
            #pragma unroll
            for (int d = 0; d < 64; ++d) s += hE[r][c * 64 + d] * wa[d];
            outE[((size_t)(r0 + r) * 3 + c) * 64 + e] = s;
        }
    }
    {                                       // inv_updates = hI @ Wo^T + bo
        const float bb = bo[tid];
        const float* wo = &Wo[tid * 256];
        #pragma unroll
        for (int r = 0; r < 4; ++r) {
            float s = 0.f;
            for (int i = 0; i < 256; i += 4) {
                f32x4_t w = *(const f32x4_t*)&wo[i];
                s += w.x * hI[r][i] + w.y * hI[r][i + 1]
                   + w.z * hI[r][i + 2] + w.w * hI[r][i + 3];
            }
            outI[(size_t)(r0 + r) * 256 + tid] = s + bb;
        }
    }
}

extern "C" void kernel_launch(void* const* d_in, const int* in_sizes, int n_in,
                              void* d_out, int out_size, void* d_ws, size_t ws_size,
                              hipStream_t stream) {
    (void)in_sizes; (void)n_in; (void)out_size; (void)ws_size;
    const float* equis = (const float*)d_in[0];
    const float* invs  = (const float*)d_in[1];
    const float* edges = (const float*)d_in[2];
    const int*   adj   = (const int*)d_in[3];
    const float* Wq = (const float*)d_in[4];
    const float* bq = (const float*)d_in[5];
    const float* Wk = (const float*)d_in[6];
    const float* bk = (const float*)d_in[7];
    const float* W1 = (const float*)d_in[8];
    const float* b1 = (const float*)d_in[9];
    const float* W2 = (const float*)d_in[10];
    const float* b2 = (const float*)d_in[11];
    const float* Wc = (const float*)d_in[12];
    const float* Wa = (const float*)d_in[13];
    const float* Wi = (const float*)d_in[14];
    const float* bi = (const float*)d_in[15];
    const float* Wo = (const float*)d_in[16];
    const float* bo = (const float*)d_in[17];

    float* out = (float*)d_out;
    float* outE    = out;                  // (B,N,3,64)  = 196608
    float* outI    = out + 196608;         // (B,N,256)   = 262144
    float* outEdge = out + 458752;         // (B,N,N,64)  = 16777216

    char* ws = (char*)d_ws;
    __bf16* W1bf = (__bf16*)(ws);                    //  98304 B (256x192)
    __bf16* W2bf = (__bf16*)(ws + 98304);            //  73728 B (144x256)
    float* qc    = (float*)(ws + 172032);            // 1048576 B
    float* kmsg  = (float*)(ws + 1220608);           //  262144 B
    float* pTE   = (float*)(ws + 1482752);           //  786432 B
    float* pTF   = (float*)(ws + 2269184);           // 1048576 B -> 3317760 total

    semla_pre<<<277, 256, 0, stream>>>(invs, equis, Wq, bq, Wk, bk, Wc, Wi, bi,
                                       W1, W2, W1bf, W2bf, qc, kmsg, pTE, pTF);
    semla_main<<<512, 512, 0, stream>>>(equis, edges, adj, W1bf, W2bf, qc, kmsg,
                                        pTE, pTF, b1, b2,
                                        outE, outI, outEdge);
    semla_post<<<256, 256, 0, stream>>>(Wa, Wo, bo, outE, outI);
}

// Round 17
// 297.745 us; speedup vs baseline: 2.0355x; 1.2549x over previous
//
#include <hip/hip_runtime.h>
#include <hip/hip_bf16.h>
#include <cstdint>

// SemlaLayer fused forward for MI355X (gfx950).
// R17 = R9 (best, 273us main) + relaxed barriers: raw s_barrier with
// lgkmcnt(0)-only waits (global stores/loads stay in flight across barriers;
// hipcc's __syncthreads drains vmcnt(0) needlessly) + s_setprio around MFMA
// clusters (T5; phase 3 has wave role-split: edge-store waves vs softmax waves).

typedef __bf16 bf16x8_t __attribute__((ext_vector_type(8)));
typedef float  f32x4_t  __attribute__((ext_vector_type(4)));

#define SP 76   // sS pitch in floats
#define KV 32   // k-tile rows

__device__ __forceinline__ int swzX(int row, int col) {   // pitch 192
    return row * 192 + (col ^ ((row & 7) << 3));
}
__device__ __forceinline__ int swzH(int row, int col) {   // pitch 256
    return (row << 8) + (col ^ ((row & 7) << 3));
}

__device__ __forceinline__ bf16x8_t cvt8(f32x4_t a, f32x4_t b) {
    bf16x8_t r;
    r[0] = (__bf16)a.x; r[1] = (__bf16)a.y; r[2] = (__bf16)a.z; r[3] = (__bf16)a.w;
    r[4] = (__bf16)b.x; r[5] = (__bf16)b.y; r[6] = (__bf16)b.z; r[7] = (__bf16)b.w;
    return r;
}

// Barrier that waits only for LDS ops (lgkmcnt), leaving global stores/loads
// in flight. Safe here: nothing across a barrier reads this wave's global
// stores, and global-load consumers get compiler-inserted vmcnt waits.
__device__ __forceinline__ void lds_barrier() {
    asm volatile("s_waitcnt lgkmcnt(0)" ::: "memory");
    __builtin_amdgcn_s_barrier();
    asm volatile("" ::: "memory");
}

// ---------------- pre-kernel ----------------
// blocks 0..255  : 4 (b,n) rows each -> kmsg, pTE, pTF (transposed), qc
// blocks 256..267: W1bf (256x192, W1 cols 64..255)
// blocks 268..276: W2bf (144x256, rows reordered: edge(72..135)|logit(0..71)|pad)
__global__ __launch_bounds__(256) void semla_pre(
    const float* __restrict__ invs, const float* __restrict__ equis,
    const float* __restrict__ Wq, const float* __restrict__ bq,
    const float* __restrict__ Wk, const float* __restrict__ bk,
    const float* __restrict__ Wc, const float* __restrict__ Wi, const float* __restrict__ bi,
    const float* __restrict__ W1, const float* __restrict__ W2,
    __bf16* __restrict__ W1bf, __bf16* __restrict__ W2bf,
    float* __restrict__ qc, float* __restrict__ kmsg,
    float* __restrict__ pTE, float* __restrict__ pTF)
{
    const int blk = blockIdx.x, tid = threadIdx.x;
    if (blk < 256) {
        const int r0 = blk * 4;
        __shared__ __align__(16) float sInv4[4][256];
        __shared__ __align__(16) float sEqu4[4][192];
        __shared__ __align__(16) float sQm4[4][64];
        #pragma unroll
        for (int j = 0; j < 4; ++j) {
            sInv4[j][tid] = invs[(size_t)(r0 + j) * 256 + tid];
            if (tid < 192) sEqu4[j][tid] = equis[(size_t)(r0 + j) * 192 + tid];
        }
        __syncthreads();
        {   // projF = invs @ Wi.T + bi  -> pTF[b][f][n]
            float acc[4] = {0.f, 0.f, 0.f, 0.f};
            const float* w = &Wi[tid * 256];
            for (int i = 0; i < 256; i += 4) {
                f32x4_t ww = *(const f32x4_t*)&w[i];
                #pragma unroll
                for (int j = 0; j < 4; ++j) {
                    const float* x = &sInv4[j][i];
                    acc[j] += ww.x * x[0] + ww.y * x[1] + ww.z * x[2] + ww.w * x[3];
                }
            }
            const float bb = bi[tid];
            #pragma unroll
            for (int j = 0; j < 4; ++j) {
                const int bb_ = (r0 + j) >> 8, nl = (r0 + j) & 255;
                pTF[((size_t)bb_ * 256 + tid) * 256 + nl] = acc[j] + bb;
            }
        }
        if (tid < 128) {   // qmsg (to LDS) / kmsg (to global)
            const int d = tid & 63;
            const float* w = (tid < 64) ? &Wq[d * 256] : &Wk[d * 256];
            float acc[4] = {0.f, 0.f, 0.f, 0.f};
            for (int i = 0; i < 256; i += 4) {
                f32x4_t ww = *(const f32x4_t*)&w[i];
                #pragma unroll
                for (int j = 0; j < 4; ++j) {
                    const float* x = &sInv4[j][i];
                    acc[j] += ww.x * x[0] + ww.y * x[1] + ww.z * x[2] + ww.w * x[3];
                }
            }
            if (tid < 64) {
                const float bb = bq[d];
                #pragma unroll
                for (int j = 0; j < 4; ++j) sQm4[j][d] = acc[j] + bb;
            } else {
                const float bb = bk[d];
                #pragma unroll
                for (int j = 0; j < 4; ++j) kmsg[(size_t)(r0 + j) * 64 + d] = acc[j] + bb;
            }
        }
        if (tid < 192) {   // projE = equis @ Wc.T -> pTE[b][c][d][n]
            const int c = tid >> 6, e = tid & 63;
            const float* w = &Wc[e * 64];
            float acc[4] = {0.f, 0.f, 0.f, 0.f};
            for (int dd = 0; dd < 64; dd += 4) {
                f32x4_t ww = *(const f32x4_t*)&w[dd];
                #pragma unroll
                for (int j = 0; j < 4; ++j) {
                    const float* x = &sEqu4[j][c * 64 + dd];
                    acc[j] += ww.x * x[0] + ww.y * x[1] + ww.z * x[2] + ww.w * x[3];
                }
            }
            #pragma unroll
            for (int j = 0; j < 4; ++j) {
                const int bb_ = (r0 + j) >> 8, nl = (r0 + j) & 255;
                pTE[(((size_t)bb_ * 3 + c) * 64 + e) * 256 + nl] = acc[j];
            }
        }
        __syncthreads();   // sQm4 ready
        {   // qc[r][o] = sum_{d<64} W1[o][d] * qmsg[r][d]
            const float* w = &W1[tid * 256];
            float acc[4] = {0.f, 0.f, 0.f, 0.f};
            for (int d = 0; d < 64; d += 4) {
                f32x4_t ww = *(const f32x4_t*)&w[d];
                #pragma unroll
                for (int j = 0; j < 4; ++j) {
                    const float* x = &sQm4[j][d];
                    acc[j] += ww.x * x[0] + ww.y * x[1] + ww.z * x[2] + ww.w * x[3];
                }
            }
            #pragma unroll
            for (int j = 0; j < 4; ++j) qc[(size_t)(r0 + j) * 256 + tid] = acc[j];
        }
    } else if (blk < 268) {   // W1bf: 256x192, source col 64+k
        const int base = (blk - 256) * 4096;
        #pragma unroll
        for (int it = 0; it < 16; ++it) {
            const int e = base + it * 256 + tid;   // < 49152
            const int o = e / 192, k = e % 192;
            W1bf[e] = (__bf16)W1[o * 256 + 64 + k];
        }
    } else if (blk < 277) {   // W2bf reordered
        const int base = (blk - 268) * 4096;
        #pragma unroll
        for (int it = 0; it < 16; ++it) {
            const int e = base + it * 256 + tid;   // < 36864
            const int o = e >> 8, cc = e & 255;
            const int src = (o < 64) ? (72 + o) : (o < 136 ? o - 64 : -1);
            W2bf[e] = (src >= 0) ? (__bf16)W2[src * 256 + cc] : (__bf16)0.f;
        }
    }
}

// ---------------- main fused kernel: one 8-wave workgroup per (b,q) ---------
__global__ __launch_bounds__(512, 2) void semla_main(
    const float* __restrict__ equis, const float* __restrict__ edges,
    const int* __restrict__ adj,
    const __bf16* __restrict__ W1bf, const __bf16* __restrict__ W2bf,
    const float* __restrict__ qc, const float* __restrict__ kmsg,
    const float* __restrict__ pTE, const float* __restrict__ pTF,
    const float* __restrict__ b1, const float* __restrict__ b2,
    float* __restrict__ outE, float* __restrict__ outI, float* __restrict__ outEdge)
{
    const int bqid = ((blockIdx.x & 7) << 7) | (blockIdx.x >> 3);  // XCD swizzle
    const int b = bqid >> 8;
    const int tid = threadIdx.x;
    const int wave = tid >> 6, lane = tid & 63;
    const int arow = lane & 15, kgrp = lane >> 4;

    __shared__ __align__(16) __bf16 sX[KV * 192];   // 12KB X tile (K=192)
    __shared__ __align__(16) __bf16 sH[KV * 256];   // 16KB H tile
    __shared__ __align__(16) float  sS[KV * SP];    // p values
    __shared__ __align__(16) float  sB1[256];
    __shared__ __align__(16) float  sB2[144];
    __shared__ __align__(16) float  sEquiQ[192];
    __shared__ float sF[72], sL[72], sL2[72];
    __shared__ int   sAdj[KV];

    if (tid < 256) sB1[tid] = b1[tid] + qc[(size_t)bqid * 256 + tid];
    if (tid < 144) sB2[tid] = (tid < 64) ? b2[72 + tid] : (tid < 136 ? b2[tid - 64] : 0.f);
    if (tid < 192) sEquiQ[tid] = equis[(size_t)bqid * 192 + tid];

    // ---- loop-invariant weights in registers ----
    bf16x8_t w1r[6][2];                 // 32 FF cols per wave, K=192
    #pragma unroll
    for (int ks = 0; ks < 6; ++ks)
        #pragma unroll
        for (int cf = 0; cf < 2; ++cf)
            w1r[ks][cf] = *(const bf16x8_t*)
                &W1bf[((wave << 5) + (cf << 4) + arow) * 192 + ks * 32 + (kgrp << 3)];
    bf16x8_t w2r[8], w2r2[8];           // wave w: tile w; wave 7 also tile 8
    #pragma unroll
    for (int ks = 0; ks < 8; ++ks)
        w2r[ks] = *(const bf16x8_t*)
            &W2bf[(((wave << 4) + arow) << 8) + ks * 32 + (kgrp << 3)];
    if (wave == 7) {
        #pragma unroll
        for (int ks = 0; ks < 8; ++ks)
            w2r2[ks] = *(const bf16x8_t*)
                &W2bf[((128 + arow) << 8) + ks * 32 + (kgrp << 3)];
    }

    // persistent per-thread state
    float m_run = -1e30f, l_run = 0.f, l2_run = 0.f;     // waves 4-7: ch=(wave-4)*16+arow
    float m_rn2 = -1e30f, l_rn2 = 0.f, l2_rn2 = 0.f;     // wave 7, arow<8: ch=64+arow
    float accE = 0.f;                                     // tid<192: (c_e,d_e)
    float accI = 0.f;                                     // tid>=256: fidx
    const int c_e = tid >> 6, d_e = tid & 63;
    const int fidx = tid - 256, h_i = (tid - 256) >> 5;

    lds_barrier();                         // init LDS visible

    for (int kt = 0; kt < 8; ++kt) {
        const int k0 = kt * KV;
        const int kb = b * 256 + k0;

        // ---- phase 1: stage X[kt] (+adj) and passB(kt-1) ----
        #pragma unroll
        for (int gi = 0; gi < 2; ++gi) {
            const int g = (gi == 0) ? tid : 512 + tid;
            if (gi == 1 && tid >= 256) continue;
            const int row = g / 24, c8 = (g % 24) << 3;
            if (c8 < 64) {
                const float* p = &kmsg[(size_t)(kb + row) * 64 + c8];
                *(bf16x8_t*)&sX[swzX(row, c8)] =
                    cvt8(*(const f32x4_t*)p, *(const f32x4_t*)(p + 4));
            } else if (c8 < 128) {
                const int d0 = c8 - 64;
                const float* ek = &equis[(size_t)(kb + row) * 192 + d0];
                f32x4_t e0a = *(const f32x4_t*)(ek),       e0b = *(const f32x4_t*)(ek + 4);
                f32x4_t e1a = *(const f32x4_t*)(ek + 64),  e1b = *(const f32x4_t*)(ek + 68);
                f32x4_t e2a = *(const f32x4_t*)(ek + 128), e2b = *(const f32x4_t*)(ek + 132);
                f32x4_t q0a = *(const f32x4_t*)&sEquiQ[d0],       q0b = *(const f32x4_t*)&sEquiQ[d0 + 4];
                f32x4_t q1a = *(const f32x4_t*)&sEquiQ[64 + d0],  q1b = *(const f32x4_t*)&sEquiQ[68 + d0];
                f32x4_t q2a = *(const f32x4_t*)&sEquiQ[128 + d0], q2b = *(const f32x4_t*)&sEquiQ[132 + d0];
                *(bf16x8_t*)&sX[swzX(row, c8)] =
                    cvt8(e0a * q0a + e1a * q1a + e2a * q2a,
                         e0b * q0b + e1b * q1b + e2b * q2b);
            } else {
                const float* p = &edges[((size_t)bqid * 256 + k0 + row) * 64 + (c8 - 128)];
                *(bf16x8_t*)&sX[swzX(row, c8)] =
                    cvt8(*(const f32x4_t*)p, *(const f32x4_t*)(p + 4));
            }
        }
        if (tid < KV) sAdj[tid] = adj[(size_t)bqid * 256 + k0 + tid];
        if (kt > 0) {
            const int k0P = k0 - KV;
            if (tid < 192) {
                float a = accE * sF[d_e];
                const float* pe = &pTE[(((size_t)b * 3 + c_e) * 64 + d_e) * 256 + k0P];
                #pragma unroll
                for (int t = 0; t < 8; ++t) {
                    f32x4_t w = *(const f32x4_t*)&pe[t * 4];
                    a += sS[(4 * t + 0) * SP + d_e] * w.x;
                    a += sS[(4 * t + 1) * SP + d_e] * w.y;
                    a += sS[(4 * t + 2) * SP + d_e] * w.z;
                    a += sS[(4 * t + 3) * SP + d_e] * w.w;
                }
                accE = a;
            }
            if (tid >= 256) {
                float a = accI * sF[64 + h_i];
                const float* pf = &pTF[((size_t)b * 256 + fidx) * 256 + k0P];
                #pragma unroll
                for (int t = 0; t < 8; ++t) {
                    f32x4_t w = *(const f32x4_t*)&pf[t * 4];
                    a += sS[(4 * t + 0) * SP + 64 + h_i] * w.x;
                    a += sS[(4 * t + 1) * SP + 64 + h_i] * w.y;
                    a += sS[(4 * t + 2) * SP + 64 + h_i] * w.z;
                    a += sS[(4 * t + 3) * SP + 64 + h_i] * w.w;
                }
                accI = a;
            }
        }
        lds_barrier();                     // (A) X staged, passB(kt-1) done

        // ---- phase 2: GEMM1 (K=192, W1 in regs) + silu -> sH ----
        f32x4_t acc1[2][2];
        {
            const f32x4_t z = {0.f, 0.f, 0.f, 0.f};
            acc1[0][0] = z; acc1[0][1] = z; acc1[1][0] = z; acc1[1][1] = z;
        }
        __builtin_amdgcn_s_setprio(1);
        #pragma unroll
        for (int ks = 0; ks < 6; ++ks) {
            const int kk = ks * 32 + (kgrp << 3);
            bf16x8_t a0 = *(const bf16x8_t*)&sX[swzX(arow, kk)];
            bf16x8_t a1 = *(const bf16x8_t*)&sX[swzX(16 + arow, kk)];
            acc1[0][0] = __builtin_amdgcn_mfma_f32_16x16x32_bf16(a0, w1r[ks][0], acc1[0][0], 0, 0, 0);
            acc1[0][1] = __builtin_amdgcn_mfma_f32_16x16x32_bf16(a0, w1r[ks][1], acc1[0][1], 0, 0, 0);
            acc1[1][0] = __builtin_amdgcn_mfma_f32_16x16x32_bf16(a1, w1r[ks][0], acc1[1][0], 0, 0, 0);
            acc1[1][1] = __builtin_amdgcn_mfma_f32_16x16x32_bf16(a1, w1r[ks][1], acc1[1][1], 0, 0, 0);
        }
        __builtin_amdgcn_s_setprio(0);
        #pragma unroll
        for (int rt = 0; rt < 2; ++rt)
            #pragma unroll
            for (int cf = 0; cf < 2; ++cf) {
                const int ccol = (wave << 5) + (cf << 4) + arow;
                const float bb = sB1[ccol];
                #pragma unroll
                for (int j = 0; j < 4; ++j) {
                    const int row = (rt << 4) + (kgrp << 2) + j;
                    float x = acc1[rt][cf][j] + bb;
                    sH[swzH(row, ccol)] = (__bf16)(x / (1.f + __expf(-x)));
                }
            }
        lds_barrier();                     // (B) H ready

        // ---- phase 3: GEMM2 + edge stores + IN-REGISTER softmax -> p ----
        f32x4_t acc2[2], acc2b[2];
        {
            const f32x4_t z = {0.f, 0.f, 0.f, 0.f};
            acc2[0] = z; acc2[1] = z; acc2b[0] = z; acc2b[1] = z;
        }
        __builtin_amdgcn_s_setprio(1);
        #pragma unroll
        for (int ks = 0; ks < 8; ++ks) {
            const int kk = ks * 32 + (kgrp << 3);
            bf16x8_t a0 = *(const bf16x8_t*)&sH[swzH(arow, kk)];
            bf16x8_t a1 = *(const bf16x8_t*)&sH[swzH(16 + arow, kk)];
            acc2[0] = __builtin_amdgcn_mfma_f32_16x16x32_bf16(a0, w2r[ks], acc2[0], 0, 0, 0);
            acc2[1] = __builtin_amdgcn_mfma_f32_16x16x32_bf16(a1, w2r[ks], acc2[1], 0, 0, 0);
            if (wave == 7) {
                acc2b[0] = __builtin_amdgcn_mfma_f32_16x16x32_bf16(a0, w2r2[ks], acc2b[0], 0, 0, 0);
                acc2b[1] = __builtin_amdgcn_mfma_f32_16x16x32_bf16(a1, w2r2[ks], acc2b[1], 0, 0, 0);
            }
        }
        __builtin_amdgcn_s_setprio(0);
        const int col = (wave << 4) + arow;
        if (wave < 4) {
            // edge channels: direct store (left in flight across barriers)
            const float bb2 = sB2[col];
            #pragma unroll
            for (int rt = 0; rt < 2; ++rt)
                #pragma unroll
                for (int j = 0; j < 4; ++j) {
                    const int r = (rt << 4) + (kgrp << 2) + j;
                    outEdge[((size_t)bqid * 256 + k0 + r) * 64 + col] = acc2[rt][j] + bb2;
                }
        } else {
            // logit channel ch: this wave holds ALL 32 rows across kgrp lanes
            const int ch = col - 64;
            const float bb2 = sB2[col];
            float s_[8]; int ad_[8];
            float xm = -1e30f;
            #pragma unroll
            for (int rt = 0; rt < 2; ++rt)
                #pragma unroll
                for (int j = 0; j < 4; ++j) {
                    const int r = (rt << 4) + (kgrp << 2) + j;
                    const float v = acc2[rt][j] + bb2;
                    s_[rt * 4 + j] = v;
                    ad_[rt * 4 + j] = sAdj[r];
                    if (ad_[rt * 4 + j]) xm = fmaxf(xm, v);
                }
            xm = fmaxf(xm, __shfl_xor(xm, 16));
            xm = fmaxf(xm, __shfl_xor(xm, 32));
            const float mN = fmaxf(m_run, xm);
            const float f = __expf(m_run - mN);
            float s1 = 0.f, s2 = 0.f;
            #pragma unroll
            for (int rt = 0; rt < 2; ++rt)
                #pragma unroll
                for (int j = 0; j < 4; ++j) {
                    const int r = (rt << 4) + (kgrp << 2) + j;
                    const float p = ad_[rt * 4 + j] ? __expf(s_[rt * 4 + j] - mN) : 0.f;
                    sS[r * SP + ch] = p;
                    s1 += p; s2 += p * p;
                }
            s1 += __shfl_xor(s1, 16); s1 += __shfl_xor(s1, 32);
            s2 += __shfl_xor(s2, 16); s2 += __shfl_xor(s2, 32);
            l_run = l_run * f + s1;
            l2_run = l2_run * f * f + s2;
            m_run = mN;
            if (kgrp == 0) sF[ch] = f;
        }
        if (wave == 7) {
            // tile 8: logit channels 64..71 (lanes arow<8 meaningful)
            const float bb3 = sB2[128 + (arow & 7)];
            float s_[8]; int ad_[8];
            float xm = -1e30f;
            #pragma unroll
            for (int rt = 0; rt < 2; ++rt)
                #pragma unroll
                for (int j = 0; j < 4; ++j) {
                    const int r = (rt << 4) + (kgrp << 2) + j;
                    const float v = acc2b[rt][j] + bb3;
                    s_[rt * 4 + j] = v;
                    ad_[rt * 4 + j] = sAdj[r];
                    if (ad_[rt * 4 + j]) xm = fmaxf(xm, v);
                }
            xm = fmaxf(xm, __shfl_xor(xm, 16));
            xm = fmaxf(xm, __shfl_xor(xm, 32));
            const float mN = fmaxf(m_rn2, xm);
            const float f = __expf(m_rn2 - mN);
            float s1 = 0.f, s2 = 0.f;
            #pragma unroll
            for (int rt = 0; rt < 2; ++rt)
                #pragma unroll
                for (int j = 0; j < 4; ++j) {
                    const int r = (rt << 4) + (kgrp << 2) + j;
                    const float p = ad_[rt * 4 + j] ? __expf(s_[rt * 4 + j] - mN) : 0.f;
                    if (arow < 8) sS[r * SP + 64 + arow] = p;
                    s1 += p; s2 += p * p;
                }
            s1 += __shfl_xor(s1, 16); s1 += __shfl_xor(s1, 32);
            s2 += __shfl_xor(s2, 16); s2 += __shfl_xor(s2, 32);
            l_rn2 = l_rn2 * f + s1;
            l2_rn2 = l2_rn2 * f * f + s2;
            m_rn2 = mN;
            if (kgrp == 0 && arow < 8) sF[64 + arow] = f;
        }
        lds_barrier();                     // (C) p + sF ready
    }

    // ---- final passB (kt=7 tile) ----
    {
        const int k0P = 224;
        if (tid < 192) {
            float a = accE * sF[d_e];
            const float* pe = &pTE[(((size_t)b * 3 + c_e) * 64 + d_e) * 256 + k0P];
            #pragma unroll
            for (int t = 0; t < 8; ++t) {
                f32x4_t w = *(const f32x4_t*)&pe[t * 4];
                a += sS[(4 * t + 0) * SP + d_e] * w.x;
                a += sS[(4 * t + 1) * SP + d_e] * w.y;
                a += sS[(4 * t + 2) * SP + d_e] * w.z;
                a += sS[(4 * t + 3) * SP + d_e] * w.w;
            }
            accE = a;
        }
        if (tid >= 256) {
            float a = accI * sF[64 + h_i];
            const float* pf = &pTF[((size_t)b * 256 + fidx) * 256 + k0P];
            #pragma unroll
            for (int t = 0; t < 8; ++t) {
                f32x4_t w = *(const f32x4_t*)&pf[t * 4];
                a += sS[(4 * t + 0) * SP + 64 + h_i] * w.x;
                a += sS[(4 * t + 1) * SP + 64 + h_i] * w.y;
                a += sS[(4 * t + 2) * SP + 64 + h_i] * w.z;
                a += sS[(4 * t + 3) * SP + 64 + h_i] * w.w;
            }
            accI = a;
        }
    }

    // ---- finalize: publish l, l2; write pre-GEMV outputs ----
    if (wave >= 4 && kgrp == 0) {
        const int ch = ((wave - 4) << 4) + arow;
        sL[ch] = l_run; sL2[ch] = l2_run;
        if (wave == 7 && arow < 8) { sL[64 + arow] = l_rn2; sL2[64 + arow] = l2_rn2; }
    }
    lds_barrier();
    if (tid < 192) {
        const float ll = sL[d_e];
        outE[(size_t)bqid * 192 + tid] = accE * sqrtf(sL2[d_e]) / (ll * ll);
    }
    if (tid >= 256) {
        const float ll = sL[64 + h_i];
        outI[(size_t)bqid * 256 + fidx] = accI * sqrtf(sL2[64 + h_i]) / (ll * ll);
    }
}

// ---------------- post-kernel: final Wa / Wo GEMVs, in place ----------------
__global__ __launch_bounds__(256) void semla_post(
    const float* __restrict__ Wa, const float* __restrict__ Wo,
    const float* __restrict__ bo,
    float* __restrict__ outE, float* __restrict__ outI)
{
    __shared__ __align__(16) float hE[4][192];
    __shared__ __align__(16) float hI[4][256];
    const int blk = blockIdx.x, tid = threadIdx.x;
    const int r0 = blk * 4;
    #pragma unroll
    for (int r = 0; r < 4; ++r) {
        if (tid < 192) hE[r][tid] = outE[(size_t)(r0 + r) * 192 + tid];
        hI[r][tid] = outI[(size_t)(r0 + r) * 256 + tid];
    }
    __syncthreads();
    if (tid < 192) {                        // equi_updates = hE @ Wa^T
        const int c = tid >> 6, e = tid & 63;
        float wa[64];
        #pragma unroll
        for (int d = 0; d < 64; d += 4) {
            f32x4_t w = *(const f32x4_t*)&Wa[e * 64 + d];
            wa[d] = w.x; wa[d + 1] = w.y; wa[d + 2] = w.z; wa[d + 3] = w.w;
        }
        #pragma unroll
        for (int r = 0; r < 4; ++r) {
            float s = 0.f;
            #pragma unroll
            for (int d = 0; d < 64; ++d) s += hE[r][c * 64 + d] * wa[d];
            outE[((size_t)(r0 + r) * 3 + c) * 64 + e] = s;
        }
    }
    {                                       // inv_updates = hI @ Wo^T + bo
        const float bb = bo[tid];
        const float* wo = &Wo[tid * 256];
        #pragma unroll
        for (int r = 0; r < 4; ++r) {
            float s = 0.f;
            for (int i = 0; i < 256; i += 4) {
                f32x4_t w = *(const f32x4_t*)&wo[i];
                s += w.x * hI[r][i] + w.y * hI[r][i + 1]
                   + w.z * hI[r][i + 2] + w.w * hI[r][i + 3];
            }
            outI[(size_t)(r0 + r) * 256 + tid] = s + bb;
        }
    }
}

extern "C" void kernel_launch(void* const* d_in, const int* in_sizes, int n_in,
                              void* d_out, int out_size, void* d_ws, size_t ws_size,
                              hipStream_t stream) {
    (void)in_sizes; (void)n_in; (void)out_size; (void)ws_size;
    const float* equis = (const float*)d_in[0];
    const float* invs  = (const float*)d_in[1];
    const float* edges = (const float*)d_in[2];
    const int*   adj   = (const int*)d_in[3];
    const float* Wq = (const float*)d_in[4];
    const float* bq = (const float*)d_in[5];
    const float* Wk = (const float*)d_in[6];
    const float* bk = (const float*)d_in[7];
    const float* W1 = (const float*)d_in[8];
    const float* b1 = (const float*)d_in[9];
    const float* W2 = (const float*)d_in[10];
    const float* b2 = (const float*)d_in[11];
    const float* Wc = (const float*)d_in[12];
    const float* Wa = (const float*)d_in[13];
    const float* Wi = (const float*)d_in[14];
    const float* bi = (const float*)d_in[15];
    const float* Wo = (const float*)d_in[16];
    const float* bo = (const float*)d_in[17];

    float* out = (float*)d_out;
    float* outE    = out;                  // (B,N,3,64)  = 196608
    float* outI    = out + 196608;         // (B,N,256)   = 262144
    float* outEdge = out + 458752;         // (B,N,N,64)  = 16777216

    char* ws = (char*)d_ws;
    __bf16* W1bf = (__bf16*)(ws);                    //  98304 B (256x192)
    __bf16* W2bf = (__bf16*)(ws + 98304);            //  73728 B (144x256)
    float* qc    = (float*)(ws + 172032);            // 1048576 B
    float* kmsg  = (float*)(ws + 1220608);           //  262144 B
    float* pTE   = (float*)(ws + 1482752);           //  786432 B
    float* pTF   = (float*)(ws + 2269184);           // 1048576 B -> 3317760 total

    semla_pre<<<277, 256, 0, stream>>>(invs, equis, Wq, bq, Wk, bk, Wc, Wi, bi,
                                       W1, W2, W1bf, W2bf, qc, kmsg, pTE, pTF);
    semla_main<<<1024, 512, 0, stream>>>(equis, edges, adj, W1bf, W2bf, qc, kmsg,
                                         pTE, pTF, b1, b2,
                                         outE, outI, outEdge);
    semla_post<<<256, 256, 0, stream>>>(Wa, Wo, bo, outE, outI);
}